// Round 10
// baseline (4640.315 us; speedup 1.0000x reference)
//
#include <hip/hip_runtime.h>
#include <hip/hip_bf16.h>
#include <stdint.h>

typedef __hip_bfloat16 bf16;
typedef __attribute__((ext_vector_type(8))) short short8;
typedef __attribute__((ext_vector_type(4))) float f32x4;
typedef __attribute__((ext_vector_type(4))) unsigned int u32x4;

#define NB   64
#define NT   2048
#define NV   32000
#define ND   256
#define NH4  1024
#define NCLS 27
#define POIS 0x7F807F80u

// ---------------- dtype conversion / packing ----------------

__global__ __launch_bounds__(256) void k_cvt_embed(const float* __restrict__ e,
                                                   bf16* __restrict__ o) {
  int i = blockIdx.x * blockDim.x + threadIdx.x;
  float4 v = reinterpret_cast<const float4*>(e)[i];
  union { bf16 h[4]; uint2 u; } pk;
  pk.h[0] = __float2bfloat16(v.x);
  pk.h[1] = __float2bfloat16(v.y);
  pk.h[2] = __float2bfloat16(v.z);
  pk.h[3] = __float2bfloat16(v.w);
  reinterpret_cast<uint2*>(o)[i] = pk.u;
}

// Wi [256][1024] f32 -> Wi_t [1024][256] bf16
__global__ __launch_bounds__(256) void k_cvt_wi(const float* __restrict__ wi,
                                                bf16* __restrict__ wit) {
  int i = blockIdx.x * blockDim.x + threadIdx.x;
  int col = i >> 8;
  int k   = i & 255;
  wit[i] = __float2bfloat16(wi[k * NH4 + col]);
}

// Wh [256][1024] f32 -> packed MFMA B-fragments
__global__ __launch_bounds__(256) void k_cvt_whp(const float* __restrict__ wh,
                                                 bf16* __restrict__ whp) {
  int idx  = blockIdx.x * blockDim.x + threadIdx.x;
  int i    = idx & 7;
  int lane = (idx >> 3) & 63;
  int kg   = (idx >> 9) & 7;
  int nt   = idx >> 12;
  int k = kg * 32 + (lane >> 4) * 8 + i;
  int n = nt * 16 + (lane & 15);
  whp[idx] = __float2bfloat16(wh[k * NH4 + n]);
}

// poison h slots 1..tn + handshake words (each chunk) -> replay-deterministic
__global__ __launch_bounds__(256) void k_poison(unsigned* __restrict__ hb, int ndw) {
  int i = blockIdx.x * blockDim.x + threadIdx.x;
  if (i < 16) hb[i] = 0xFFFFFFFFu;    // XCD-handshake words (slot-0 head, unused otherwise)
  if (i < ndw) hb[8192 + i] = POIS;   // slots 1..tn
}

// ---------------- zx = embed[tokens] @ Wi, written PERMUTED ----------------
__global__ __launch_bounds__(256) void k_gemm_zx(const int*  __restrict__ tokens,
                                                 const bf16* __restrict__ eb,
                                                 const bf16* __restrict__ wit,
                                                 char* __restrict__ zxp,
                                                 int t0, int lgch) {
  __shared__ bf16 As[4 * 64 * 8];
  __shared__ bf16 Bs[4 * 64 * 8];
  int bid  = blockIdx.x;
  int nb   = bid & 15;
  int mb   = bid >> 4;
  int m0   = mb * 64, n0 = nb * 64;
  int tid  = threadIdx.x, lane = tid & 63, wave = tid >> 6;
  int wm   = wave >> 1, wn = wave & 1;
  int srow = tid >> 2;
  int skg  = tid & 3;

  int r    = m0 + srow;
  int bidx = r >> lgch;
  int lt   = r & ((1 << lgch) - 1);
  long trow = (long)tokens[bidx * NT + t0 + lt] * ND;
  const bf16* ap = eb  + trow + skg * 8;
  const bf16* bp = wit + (long)(n0 + srow) * ND + skg * 8;
  bf16* as_dst = &As[(skg * 64 + srow) * 8];
  bf16* bs_dst = &Bs[(skg * 64 + srow) * 8];

  f32x4 acc[2][2] = {};
  for (int k0 = 0; k0 < ND; k0 += 32) {
    __syncthreads();
    *(u32x4*)as_dst = *(const u32x4*)(ap + k0);
    *(u32x4*)bs_dst = *(const u32x4*)(bp + k0);
    __syncthreads();
    short8 a0 = *(const short8*)&As[((lane >> 4) * 64 + wm * 32 +  0 + (lane & 15)) * 8];
    short8 a1 = *(const short8*)&As[((lane >> 4) * 64 + wm * 32 + 16 + (lane & 15)) * 8];
    short8 b0 = *(const short8*)&Bs[((lane >> 4) * 64 + wn * 32 +  0 + (lane & 15)) * 8];
    short8 b1 = *(const short8*)&Bs[((lane >> 4) * 64 + wn * 32 + 16 + (lane & 15)) * 8];
    acc[0][0] = __builtin_amdgcn_mfma_f32_16x16x32_bf16(a0, b0, acc[0][0], 0, 0, 0);
    acc[0][1] = __builtin_amdgcn_mfma_f32_16x16x32_bf16(a0, b1, acc[0][1], 0, 0, 0);
    acc[1][0] = __builtin_amdgcn_mfma_f32_16x16x32_bf16(a1, b0, acc[1][0], 0, 0, 0);
    acc[1][1] = __builtin_amdgcn_mfma_f32_16x16x32_bf16(a1, b1, acc[1][1], 0, 0, 0);
  }
  int r_base = m0 + wm * 32 + (lane >> 4) * 4;
  int c_base = n0 + wn * 32 + (lane & 15);
  int mask = (1 << lgch) - 1;
#pragma unroll
  for (int fm = 0; fm < 2; ++fm)
#pragma unroll
    for (int fn = 0; fn < 2; ++fn)
#pragma unroll
      for (int i2 = 0; i2 < 4; ++i2) {
        int rr  = r_base + fm * 16 + i2;
        int col = c_base + fn * 16;
        int b   = rr >> lgch, lt2 = rr & mask;
        int q   = col >> 8, gg = (col >> 4) & 15, uu = col & 15;
        int w_  = b >> 4, rq_ = (b >> 2) & 3, ii = b & 3;
        size_t off = (size_t)lt2 * 131072 + gg * 8192 + w_ * 2048 + rq_ * 512 +
                     ii * 128 + uu * 8 + q * 2;
        *(bf16*)(zxp + off) = __float2bfloat16(acc[fm][fn][i2]);
      }
}

// ---------------- LSTM scan, pairwise exchange ----------------
// 16 blocks; active: p = bid&7 in [0,4), s = bid>>3; pair (bid, bid^8) lands on
// the same XCD under round-robin (verified at runtime via HW_REG_XCC_ID).
// Publish: agent atomics (always, coherence point = L3). Poll: if same-XCD,
// sc0 plain loads served by the shared L2 (fast); bounded spin falls back
// permanently to agent-atomic polling (correct regardless of placement).
__device__ __forceinline__ float sigf(float x) {
  return __builtin_amdgcn_rcpf(1.f + __expf(-x));
}
__device__ __forceinline__ float tanh_fast(float x) {
  return 1.f - 2.f * __builtin_amdgcn_rcpf(1.f + __expf(2.f * x));
}
__device__ __forceinline__ unsigned short f2b(float x) {
  bf16 t = __float2bfloat16(x);
  return *reinterpret_cast<unsigned short*>(&t);
}

union Frag { unsigned long long q[2]; short8 s; };

__device__ __forceinline__ bool frag_bad(const Frag fr[4]) {
  bool bad = false;
#pragma unroll
  for (int r = 0; r < 4; ++r) {
    unsigned long long q0 = fr[r].q[0], q1 = fr[r].q[1];
    bad |= ((unsigned)q0 == POIS) | ((unsigned)(q0 >> 32) == POIS) |
           ((unsigned)q1 == POIS) | ((unsigned)(q1 >> 32) == POIS);
  }
  return __any(bad);
}

#define SC0_POLL_ISSUE(fr, sb, l)                                              \
  _Pragma("unroll")                                                            \
  for (int r = 0; r < 4; ++r) {                                                \
    asm volatile("global_load_dwordx2 %0, %1, off sc0"                         \
                 : "=v"(fr[r].q[0]) : "v"(sb + (size_t)(r * 64 + l) * 2)       \
                 : "memory");                                                  \
    asm volatile("global_load_dwordx2 %0, %1, off sc0"                         \
                 : "=v"(fr[r].q[1]) : "v"(sb + (size_t)(r * 64 + l) * 2 + 1)   \
                 : "memory");                                                  \
  }

#define SC0_POLL_WAIT(fr)                                                      \
  asm volatile("s_waitcnt vmcnt(0)"                                            \
               : "+v"(fr[0].q[0]), "+v"(fr[0].q[1]), "+v"(fr[1].q[0]),         \
                 "+v"(fr[1].q[1]), "+v"(fr[2].q[0]), "+v"(fr[2].q[1]),         \
                 "+v"(fr[3].q[0]), "+v"(fr[3].q[1]));                          \
  __builtin_amdgcn_sched_barrier(0);

__global__ __launch_bounds__(512, 1) void k_lstm(const char* __restrict__ zxp,
                                                 const bf16* __restrict__ whp,
                                                 const float* __restrict__ bh,
                                                 float* __restrict__ cst,
                                                 float* __restrict__ hst,
                                                 unsigned* __restrict__ hbuf,
                                                 int t0, int tn) {
  __shared__ unsigned hs[2][1024];   // [parity][own-half 4KB in fragment layout]
  __shared__ unsigned pxcc;

  int bid = blockIdx.x;
  int p   = bid & 7;           // batch tile
  int s   = bid >> 3;          // unit half
  if (p >= 4) return;          // 8 spacer blocks (XCD alignment only)
  int tid = threadIdx.x;
  int l   = tid & 63;
  int wv  = tid >> 6;          // wave 0..7
  int G   = s * 8 + wv;        // unit group 0..15
  int l15 = l & 15, l4 = l >> 4;
  int u   = G * 16 + l15;      // this lane's unit

  // ---- XCD handshake with partner block (bid^8): pick poll protocol ----
  unsigned my_xcc;
  asm volatile("s_getreg_b32 %0, hwreg(HW_REG_XCC_ID)" : "=s"(my_xcc));
  my_xcc &= 15u;
  if (tid == 0) {
    __hip_atomic_store(&hbuf[bid], my_xcc, __ATOMIC_RELAXED, __HIP_MEMORY_SCOPE_AGENT);
    unsigned pr;
    do {
      pr = __hip_atomic_load(&hbuf[bid ^ 8], __ATOMIC_RELAXED, __HIP_MEMORY_SCOPE_AGENT);
    } while (pr == 0xFFFFFFFFu);
    pxcc = pr;
  }
  __syncthreads();
  bool fast = (pxcc == my_xcc);

  // register-resident Wh B-fragments, split own/partner k-halves.
  short8 bw_own[4][4], bw_par[4][4];
#pragma unroll
  for (int q = 0; q < 4; ++q) {
    int nt = q * 16 + G;
#pragma unroll
    for (int r = 0; r < 4; ++r) {
      bw_own[q][r] = *(const short8*)&whp[((long)(nt * 8 + (4 * s + r)) * 64 + l) * 8];
      bw_par[q][r] = *(const short8*)&whp[((long)(nt * 8 + (4 * (1 - s) + r)) * 64 + l) * 8];
    }
  }
#pragma unroll
  for (int q = 0; q < 4; ++q)
#pragma unroll
    for (int r = 0; r < 4; ++r) {
      asm volatile("" : "+v"(bw_own[q][r]));
      asm volatile("" : "+v"(bw_par[q][r]));
    }

  float bhv[4];
#pragma unroll
  for (int q = 0; q < 4; ++q) bhv[q] = bh[q * 256 + u];

  float c[4];
#pragma unroll
  for (int i = 0; i < 4; ++i)
    c[i] = (t0 == 0) ? 0.f : cst[(p * 16 + l4 * 4 + i) * 256 + u];

  // initial A-fragments of h(t0), both halves: zeros or hst
  short8 a_own[4], a_par[4];
  if (t0 == 0) {
#pragma unroll
    for (int r = 0; r < 4; ++r) { a_own[r] = (short8)(short)0; a_par[r] = (short8)(short)0; }
  } else {
    int rowb = p * 16 + l15;
#pragma unroll
    for (int r = 0; r < 4; ++r) {
      {
        const float* hp = &hst[rowb * 256 + l4 * 8 + (4 * s + r) * 32];
        float4 f0 = *(const float4*)hp;
        float4 f1 = *(const float4*)(hp + 4);
        unsigned short e[8] = {f2b(f0.x), f2b(f0.y), f2b(f0.z), f2b(f0.w),
                               f2b(f1.x), f2b(f1.y), f2b(f1.z), f2b(f1.w)};
        a_own[r] = *(const short8*)e;
      }
      {
        const float* hp = &hst[rowb * 256 + l4 * 8 + (4 * (1 - s) + r) * 32];
        float4 f0 = *(const float4*)hp;
        float4 f1 = *(const float4*)(hp + 4);
        unsigned short e[8] = {f2b(f0.x), f2b(f0.y), f2b(f0.z), f2b(f0.w),
                               f2b(f1.x), f2b(f1.y), f2b(f1.z), f2b(f1.w)};
        a_par[r] = *(const short8*)e;
      }
    }
  }

  const char* zbase = zxp + G * 8192 + p * 2048 + l4 * 512 + l15 * 8;
  unsigned long long* hb64 = (unsigned long long*)hbuf;

  // zx prefetch for step 0
  uint2 z0[4], z1[4];
#pragma unroll
  for (int i = 0; i < 4; ++i) z0[i] = *(const uint2*)(zbase + i * 128);

  // producer constants
  int hi   = (2 * G + (l15 >> 3)) & 3;
  int rown = (G >> 1) & 3;
  int jw   = (l15 & 7) >> 1;
  bool even = ((l & 1) == 0);

  for (int lt = 0; lt < tn; ++lt) {
    bool pre_top = !fast;
    // slow path: prefetch next zx at top (R9-proven position)
    if (pre_top && lt + 1 < tn) {
#pragma unroll
      for (int i = 0; i < 4; ++i)
        z1[i] = *(const uint2*)(zbase + (size_t)(lt + 1) * 131072 + i * 128);
    }

    // own half A-fragments from LDS (written last iter, parity lt&1)
    if (lt > 0) {
      const unsigned* hp = hs[lt & 1];
#pragma unroll
      for (int r = 0; r < 4; ++r)
        a_own[r] = *(const short8*)&hp[(r * 64 + l) * 4];
    }

    Frag fr[4];
    unsigned long long* sb = hb64 + (size_t)lt * 4096 + p * 1024 + (1 - s) * 512;
    // fast path: issue sc0 poll loads EARLY; latency hides under own-MFMAs
    if (fast && lt > 0) {
      SC0_POLL_ISSUE(fr, sb, l)
    }

    // own-half MFMAs
    f32x4 acc[4] = {};
#pragma unroll
    for (int r = 0; r < 4; ++r) {
#pragma unroll
      for (int q = 0; q < 4; ++q)
        acc[q] = __builtin_amdgcn_mfma_f32_16x16x32_bf16(a_own[r], bw_own[q][r],
                                                         acc[q], 0, 0, 0);
    }

    if (lt > 0) {
      bool got = false;
      if (fast) {
        __builtin_amdgcn_sched_barrier(0);
        SC0_POLL_WAIT(fr)
        got = !frag_bad(fr);
        for (int spin = 0; !got && spin < 512; ++spin) {
          SC0_POLL_ISSUE(fr, sb, l)
          SC0_POLL_WAIT(fr)
          got = !frag_bad(fr);
        }
        if (!got) fast = false;   // permanent fallback to coherent path
      }
      if (!got) {
        for (unsigned spin = 0; spin < 65536u; ++spin) {
#pragma unroll
          for (int r = 0; r < 4; ++r) {
            fr[r].q[0] = __hip_atomic_load(sb + (size_t)(r * 64 + l) * 2,
                                           __ATOMIC_RELAXED, __HIP_MEMORY_SCOPE_AGENT);
            fr[r].q[1] = __hip_atomic_load(sb + (size_t)(r * 64 + l) * 2 + 1,
                                           __ATOMIC_RELAXED, __HIP_MEMORY_SCOPE_AGENT);
          }
          if (!frag_bad(fr)) break;
        }
      }
#pragma unroll
      for (int r = 0; r < 4; ++r) a_par[r] = fr[r].s;
    }

    // fast path: prefetch next zx here (hidden under partner-MFMA+gates+barrier)
    if (!pre_top && lt + 1 < tn) {
#pragma unroll
      for (int i = 0; i < 4; ++i)
        z1[i] = *(const uint2*)(zbase + (size_t)(lt + 1) * 131072 + i * 128);
    }

#pragma unroll
    for (int r = 0; r < 4; ++r) {
#pragma unroll
      for (int q = 0; q < 4; ++q)
        acc[q] = __builtin_amdgcn_mfma_f32_16x16x32_bf16(a_par[r], bw_par[q][r],
                                                         acc[q], 0, 0, 0);
    }

    // gates: lane owns (4 batches x unit u)
    unsigned my0, my1, my2, my3;
    float hv[4];
    {
      float zi, zf, zg, zo;
      zi = acc[0][0] + __uint_as_float((z0[0].x & 0xFFFFu) << 16) + bhv[0];
      zf = acc[1][0] + __uint_as_float((z0[0].x >> 16) << 16)     + bhv[1];
      zg = acc[2][0] + __uint_as_float((z0[0].y & 0xFFFFu) << 16) + bhv[2];
      zo = acc[3][0] + __uint_as_float((z0[0].y >> 16) << 16)     + bhv[3];
      c[0] = sigf(zf) * c[0] + sigf(zi) * tanh_fast(zg);
      hv[0] = sigf(zo) * tanh_fast(c[0]);  my0 = f2b(hv[0]);
      zi = acc[0][1] + __uint_as_float((z0[1].x & 0xFFFFu) << 16) + bhv[0];
      zf = acc[1][1] + __uint_as_float((z0[1].x >> 16) << 16)     + bhv[1];
      zg = acc[2][1] + __uint_as_float((z0[1].y & 0xFFFFu) << 16) + bhv[2];
      zo = acc[3][1] + __uint_as_float((z0[1].y >> 16) << 16)     + bhv[3];
      c[1] = sigf(zf) * c[1] + sigf(zi) * tanh_fast(zg);
      hv[1] = sigf(zo) * tanh_fast(c[1]);  my1 = f2b(hv[1]);
      zi = acc[0][2] + __uint_as_float((z0[2].x & 0xFFFFu) << 16) + bhv[0];
      zf = acc[1][2] + __uint_as_float((z0[2].x >> 16) << 16)     + bhv[1];
      zg = acc[2][2] + __uint_as_float((z0[2].y & 0xFFFFu) << 16) + bhv[2];
      zo = acc[3][2] + __uint_as_float((z0[2].y >> 16) << 16)     + bhv[3];
      c[2] = sigf(zf) * c[2] + sigf(zi) * tanh_fast(zg);
      hv[2] = sigf(zo) * tanh_fast(c[2]);  my2 = f2b(hv[2]);
      zi = acc[0][3] + __uint_as_float((z0[3].x & 0xFFFFu) << 16) + bhv[0];
      zf = acc[1][3] + __uint_as_float((z0[3].x >> 16) << 16)     + bhv[1];
      zg = acc[2][3] + __uint_as_float((z0[3].y & 0xFFFFu) << 16) + bhv[2];
      zo = acc[3][3] + __uint_as_float((z0[3].y >> 16) << 16)     + bhv[3];
      c[3] = sigf(zf) * c[3] + sigf(zi) * tanh_fast(zg);
      hv[3] = sigf(zo) * tanh_fast(c[3]);  my3 = f2b(hv[3]);
    }

    // publish: UNCHANGED agent atomics (coherence point), static-index packing.
    unsigned pt0 = (unsigned)__shfl_xor((int)my0, 1, 64);
    unsigned pt1 = (unsigned)__shfl_xor((int)my1, 1, 64);
    unsigned pt2 = (unsigned)__shfl_xor((int)my2, 1, 64);
    unsigned pt3 = (unsigned)__shfl_xor((int)my3, 1, 64);
    unsigned dwA = even ? (my0 | (pt0 << 16)) : (pt2 | (my2 << 16));
    unsigned dwB = even ? (my1 | (pt1 << 16)) : (pt3 | (my3 << 16));
    int ia = even ? 0 : 2;
    unsigned* gdst = hbuf + (size_t)(lt + 1) * 8192 + p * 2048 + s * 1024;
    unsigned* ldst = hs[(lt + 1) & 1];
    int idxA = (rown * 64 + ((l4 * 4 + ia) | (hi << 4))) * 4 + jw;
    int idxB = (rown * 64 + ((l4 * 4 + ia + 1) | (hi << 4))) * 4 + jw;
    __hip_atomic_store(gdst + idxA, dwA, __ATOMIC_RELAXED, __HIP_MEMORY_SCOPE_AGENT);
    __hip_atomic_store(gdst + idxB, dwB, __ATOMIC_RELAXED, __HIP_MEMORY_SCOPE_AGENT);
    ldst[idxA] = dwA;
    ldst[idxB] = dwB;

    if (lt == tn - 1) {
#pragma unroll
      for (int i = 0; i < 4; ++i)
        hst[(p * 16 + l4 * 4 + i) * 256 + u] = hv[i];
    }

    __syncthreads();
#pragma unroll
    for (int i = 0; i < 4; ++i) z0[i] = z1[i];
  }

#pragma unroll
  for (int i = 0; i < 4; ++i)
    cst[(p * 16 + l4 * 4 + i) * 256 + u] = c[i];
}

// ---------------- y = h @ Wo + bo ----------------
__global__ __launch_bounds__(64) void k_out(const float* __restrict__ hfin,
                                            const float* __restrict__ wo,
                                            const float* __restrict__ bo,
                                            float* __restrict__ y) {
  __shared__ float hsm[256];
  int b = blockIdx.x, tid = threadIdx.x;
  for (int i = tid; i < 256; i += 64) hsm[i] = hfin[b * 256 + i];
  __syncthreads();
  if (tid < NCLS) {
    float s = bo[tid];
    for (int k = 0; k < 256; ++k) s += hsm[k] * wo[k * NCLS + tid];
    y[b * NCLS + tid] = s;
  }
}

// ---------------- launcher ----------------
extern "C" void kernel_launch(void* const* d_in, const int* in_sizes, int n_in,
                              void* d_out, int out_size, void* d_ws, size_t ws_size,
                              hipStream_t stream) {
  const int*   tokens = (const int*)d_in[0];
  const float* embed  = (const float*)d_in[3];
  const float* wi     = (const float*)d_in[4];
  const float* wh     = (const float*)d_in[5];
  const float* bh     = (const float*)d_in[6];
  const float* wo     = (const float*)d_in[7];
  const float* bo     = (const float*)d_in[8];
  float* y = (float*)d_out;

  char* ws = (char*)d_ws;
  bf16* eb     = (bf16*)ws;     ws += (size_t)NV * ND * 2;        // 16.38 MB
  bf16* wit    = (bf16*)ws;     ws += (size_t)NH4 * ND * 2;       // 0.5 MB
  bf16* whp    = (bf16*)ws;     ws += (size_t)ND * NH4 * 2;       // 0.5 MB
  float* cst   = (float*)ws;    ws += (size_t)NB * ND * 4;        // 64 KB
  float* hst   = (float*)ws;    ws += (size_t)NB * ND * 4;        // 64 KB
  size_t fixed = (size_t)(ws - (char*)d_ws);

  // pick largest chunk: need = fixed + hbuf((ch+1)*32KB) + zxp(ch*128KB)
  int CHUNK = 32, lgch = 5;
  static const int cand[]  = {2048, 1024, 512, 256, 128, 64, 32};
  static const int candl[] = {11, 10, 9, 8, 7, 6, 5};
  for (int ci = 0; ci < 7; ++ci) {
    size_t need = fixed + (size_t)(cand[ci] + 1) * 32768 + (size_t)cand[ci] * 131072;
    if (need <= ws_size) { CHUNK = cand[ci]; lgch = candl[ci]; break; }
  }
  unsigned* hbuf = (unsigned*)ws;  ws += (size_t)(CHUNK + 1) * 32768;
  char* zxp = ws;

  hipLaunchKernelGGL(k_cvt_embed, dim3(NV * ND / 4 / 256), dim3(256), 0, stream, embed, eb);
  hipLaunchKernelGGL(k_cvt_wi,    dim3(NH4 * ND / 256), dim3(256), 0, stream, wi, wit);
  hipLaunchKernelGGL(k_cvt_whp,   dim3(ND * NH4 / 256), dim3(256), 0, stream, wh, whp);

  for (int t0 = 0; t0 < NT; t0 += CHUNK) {
    hipLaunchKernelGGL(k_gemm_zx, dim3(CHUNK * 16), dim3(256), 0, stream,
                       tokens, eb, wit, zxp, t0, lgch);
    hipLaunchKernelGGL(k_poison, dim3(CHUNK * 32), dim3(256), 0, stream,
                       hbuf, CHUNK * 8192);
    hipLaunchKernelGGL(k_lstm, dim3(16), dim3(512), 0, stream,
                       zxp, whp, bh, cst, hst, hbuf, t0, CHUNK);
  }
  hipLaunchKernelGGL(k_out, dim3(NB), dim3(64), 0, stream, hst, wo, bo, y);
}

// Round 11
// 3471.971 us; speedup vs baseline: 1.3365x; 1.3365x over previous
//
#include <hip/hip_runtime.h>
#include <hip/hip_bf16.h>
#include <stdint.h>

typedef __hip_bfloat16 bf16;
typedef __attribute__((ext_vector_type(8))) short short8;
typedef __attribute__((ext_vector_type(4))) float f32x4;
typedef __attribute__((ext_vector_type(4))) int i32x4;
typedef __attribute__((ext_vector_type(4))) unsigned int u32x4;

#define NB   64
#define NT   2048
#define NV   32000
#define ND   256
#define NH4  1024
#define NCLS 27

// ---------------- dtype conversion / packing ----------------

__global__ __launch_bounds__(256) void k_cvt_embed(const float* __restrict__ e,
                                                   bf16* __restrict__ o) {
  int i = blockIdx.x * blockDim.x + threadIdx.x;
  float4 v = reinterpret_cast<const float4*>(e)[i];
  union { bf16 h[4]; uint2 u; } pk;
  pk.h[0] = __float2bfloat16(v.x);
  pk.h[1] = __float2bfloat16(v.y);
  pk.h[2] = __float2bfloat16(v.z);
  pk.h[3] = __float2bfloat16(v.w);
  reinterpret_cast<uint2*>(o)[i] = pk.u;
}

// Wi [256][1024] f32 -> Wi_t [1024][256] bf16
__global__ __launch_bounds__(256) void k_cvt_wi(const float* __restrict__ wi,
                                                bf16* __restrict__ wit) {
  int i = blockIdx.x * blockDim.x + threadIdx.x;
  int col = i >> 8;
  int k   = i & 255;
  wit[i] = __float2bfloat16(wi[k * NH4 + col]);
}

// per-column scales for i8 quantization of Wh.
// dq  = colmax/16129 (dequant of i8·i8 dot), rdq = 16129/colmax (zx -> grid),
// rw  = 127/colmax (weight quant).
__global__ __launch_bounds__(256) void k_scale(const float* __restrict__ wh,
                                               float* __restrict__ dq,
                                               float* __restrict__ rdq,
                                               float* __restrict__ rw) {
  int col = blockIdx.x * 256 + threadIdx.x;   // grid 4
  float m = 0.f;
  for (int k = 0; k < ND; ++k) m = fmaxf(m, fabsf(wh[k * NH4 + col]));
  dq[col]  = m * (1.f / 16129.f);
  rdq[col] = 16129.f / m;
  rw[col]  = 127.f / m;
}

// Wh -> i8 B-fragments for mfma_i32_16x16x64_i8:
// whq[((nt*4 + kq)*64 + lane)*16 + ii] = qi8(Wh[kq*64 + (lane>>4)*16 + ii][nt*16 + (lane&15)])
__global__ __launch_bounds__(256) void k_cvt_whq(const float* __restrict__ wh,
                                                 const float* __restrict__ rw,
                                                 signed char* __restrict__ whq) {
  int idx  = blockIdx.x * 256 + threadIdx.x;  // grid 1024, 0..262143
  int ii   = idx & 15;
  int lane = (idx >> 4) & 63;
  int kq   = (idx >> 10) & 3;
  int nt   = idx >> 12;
  int k   = kq * 64 + (lane >> 4) * 16 + ii;
  int col = nt * 16 + (lane & 15);
  whq[idx] = (signed char)(int)rintf(wh[k * NH4 + col] * rw[col]);
}

// ---------------- zx = embed[tokens] @ Wi, written as i32 in dot-grid units ----------------
// Tile rows = 64 batches at ONE step (mb). Output layout (dwords):
//   (((p<<lgch)+lt)*64 + nt)*128 + lane32*4 + ri
// where p=b>>3, r=b&7, lane32=(col&15)|((r>>2)<<4), ri=r&3 — the exact C-frag
// slots of the scan's MFMA, preloaded as the C operand.
__global__ __launch_bounds__(256) void k_gemm_zx(const int*  __restrict__ tokens,
                                                 const bf16* __restrict__ eb,
                                                 const bf16* __restrict__ wit,
                                                 const float* __restrict__ rdq,
                                                 int* __restrict__ zxq,
                                                 int t0, int lgch) {
  __shared__ bf16 As[4 * 64 * 8];
  __shared__ bf16 Bs[4 * 64 * 8];
  int bid  = blockIdx.x;
  int nb   = bid & 15;
  int mb   = bid >> 4;          // step within chunk
  int n0   = nb * 64;
  int tid  = threadIdx.x, lane = tid & 63, wave = tid >> 6;
  int wm   = wave >> 1, wn = wave & 1;
  int srow = tid >> 2;          // batch 0..63
  int skg  = tid & 3;

  long trow = (long)tokens[srow * NT + t0 + mb] * ND;
  const bf16* ap = eb  + trow + skg * 8;
  const bf16* bp = wit + (long)(n0 + srow) * ND + skg * 8;
  bf16* as_dst = &As[(skg * 64 + srow) * 8];
  bf16* bs_dst = &Bs[(skg * 64 + srow) * 8];

  f32x4 acc[2][2] = {};
  for (int k0 = 0; k0 < ND; k0 += 32) {
    __syncthreads();
    *(u32x4*)as_dst = *(const u32x4*)(ap + k0);
    *(u32x4*)bs_dst = *(const u32x4*)(bp + k0);
    __syncthreads();
    short8 a0 = *(const short8*)&As[((lane >> 4) * 64 + wm * 32 +  0 + (lane & 15)) * 8];
    short8 a1 = *(const short8*)&As[((lane >> 4) * 64 + wm * 32 + 16 + (lane & 15)) * 8];
    short8 b0 = *(const short8*)&Bs[((lane >> 4) * 64 + wn * 32 +  0 + (lane & 15)) * 8];
    short8 b1 = *(const short8*)&Bs[((lane >> 4) * 64 + wn * 32 + 16 + (lane & 15)) * 8];
    acc[0][0] = __builtin_amdgcn_mfma_f32_16x16x32_bf16(a0, b0, acc[0][0], 0, 0, 0);
    acc[0][1] = __builtin_amdgcn_mfma_f32_16x16x32_bf16(a0, b1, acc[0][1], 0, 0, 0);
    acc[1][0] = __builtin_amdgcn_mfma_f32_16x16x32_bf16(a1, b0, acc[1][0], 0, 0, 0);
    acc[1][1] = __builtin_amdgcn_mfma_f32_16x16x32_bf16(a1, b1, acc[1][1], 0, 0, 0);
  }

  int cb  = n0 + wn * 32 + (lane & 15);
  float rq0 = rdq[cb], rq1 = rdq[cb + 16];
  int bb = wm * 32 + (lane >> 4) * 4;         // batch base (multiple of 4)
#pragma unroll
  for (int fm = 0; fm < 2; ++fm) {
    int b0r = bb + fm * 16;
    int pw  = b0r >> 3;
    int hi  = ((b0r & 7) >> 2) << 4;
#pragma unroll
    for (int fn = 0; fn < 2; ++fn) {
      int col = cb + fn * 16;
      int nt  = col >> 4;
      int lane32 = (col & 15) | hi;
      float rq = fn ? rq1 : rq0;
      i32x4 v;
#pragma unroll
      for (int i = 0; i < 4; ++i) v[i] = (int)rintf(acc[fm][fn][i] * rq);
      size_t off = ((((size_t)(pw << lgch) + mb) * 64 + nt) * 32 + lane32) * 4;
      *(i32x4*)(zxq + off) = v;
    }
  }
}

// ---------------- LSTM scan: fully CU-local, i8 MFMA ----------------
// 8 WGs x 512 threads (8 waves, 1 WG/CU). WG p owns batches [8p,8p+8) x ALL
// 256 units -> NO inter-WG communication, no atomics. Wh fully register-
// resident as i8 (w[8][4] = 128 VGPR/wave). h ping-pongs through a 4KB LDS
// A-fragment buffer; z exchanged through 32KB LDS; 2 barriers/step.
// A rows 8..15 are zero padding (M=8 in a 16-row MFMA).
__device__ __forceinline__ float sigf(float x) {
  return __builtin_amdgcn_rcpf(1.f + __expf(-x));
}
__device__ __forceinline__ float tanh_fast(float x) {
  return 1.f - 2.f * __builtin_amdgcn_rcpf(1.f + __expf(2.f * x));
}

__global__ __launch_bounds__(512, 1) void k_lstm(const int* __restrict__ zxq,
                                                 const signed char* __restrict__ whq,
                                                 const float* __restrict__ dq,
                                                 const float* __restrict__ bh,
                                                 float* __restrict__ cst,
                                                 float* __restrict__ hst,
                                                 int t0, int tn, int lgch) {
  __shared__ int  zl[8 * 1024];            // [b][col] i32, 32 KB
  __shared__ signed char aF[4 * 64 * 16];  // [kq][la][16] i8 A-frags, 4 KB

  int p   = blockIdx.x;        // batches [8p, 8p+8)
  int tid = threadIdx.x;
  int l   = tid & 63;
  int wv  = tid >> 6;
  int l15 = l & 15, l4 = l >> 4;
  int u   = tid & 255;         // gate-phase unit
  int bg  = tid >> 8;          // 0/1 -> batches bg*4 .. bg*4+3

  // register-resident Wh i8 B-fragments (static indices only)
  i32x4 w[8][4];
#pragma unroll
  for (int j = 0; j < 8; ++j) {
    int nt = wv * 8 + j;
#pragma unroll
    for (int kq = 0; kq < 4; ++kq)
      w[j][kq] = *(const i32x4*)&whq[((nt * 4 + kq) * 64 + l) * 16];
  }
#pragma unroll
  for (int j = 0; j < 8; ++j)
#pragma unroll
    for (int kq = 0; kq < 4; ++kq)
      asm volatile("" : "+v"(w[j][kq]));

  float dqv[4], bhv[4], c[4];
#pragma unroll
  for (int q = 0; q < 4; ++q) { dqv[q] = dq[q * 256 + u]; bhv[q] = bh[q * 256 + u]; }
#pragma unroll
  for (int i = 0; i < 4; ++i)
    c[i] = (t0 == 0) ? 0.f : cst[(p * 8 + bg * 4 + i) * 256 + u];

  int kqu = u >> 6, lgu = (u >> 4) & 3, iiu = u & 15;

  // zero A-frag LDS (pad rows 8..15 stay zero forever)
  if (tid < 256) ((i32x4*)aF)[tid] = (i32x4)0;
  __syncthreads();
  if (t0 != 0) {
#pragma unroll
    for (int i = 0; i < 4; ++i) {
      int b = bg * 4 + i;
      int hq = (int)rintf(hst[(p * 8 + b) * 256 + u] * 127.f);
      aF[kqu * 1024 + (b | (lgu << 4)) * 16 + iiu] = (signed char)hq;
    }
  }
  __syncthreads();

  // zx preload for step 0 (i32, already in dot-grid units -> direct C operand)
  size_t zoff0 = ((size_t)(p << lgch) * 64) * 128 + (size_t)(l & 31) * 4;
  i32x4 z0[8];
#pragma unroll
  for (int j = 0; j < 8; ++j)
    z0[j] = *(const i32x4*)(zxq + zoff0 + (size_t)(wv * 8 + j) * 128);

  for (int lt = 0; lt < tn; ++lt) {
    // A-fragments from LDS
    i32x4 a0 = *(const i32x4*)&aF[0 * 1024 + l * 16];
    i32x4 a1 = *(const i32x4*)&aF[1 * 1024 + l * 16];
    i32x4 a2 = *(const i32x4*)&aF[2 * 1024 + l * 16];
    i32x4 a3 = *(const i32x4*)&aF[3 * 1024 + l * 16];

    // z = zx + h @ Wh (i32 dot, C preloaded with scaled zx)
    i32x4 acc[8];
#pragma unroll
    for (int j = 0; j < 8; ++j) {
      i32x4 t;
      t = __builtin_amdgcn_mfma_i32_16x16x64_i8(a0, w[j][0], z0[j], 0, 0, 0);
      t = __builtin_amdgcn_mfma_i32_16x16x64_i8(a1, w[j][1], t, 0, 0, 0);
      t = __builtin_amdgcn_mfma_i32_16x16x64_i8(a2, w[j][2], t, 0, 0, 0);
      acc[j] = __builtin_amdgcn_mfma_i32_16x16x64_i8(a3, w[j][3], t, 0, 0, 0);
    }

    // prefetch next step's zx into z0 (dead after C-consume above)
    if (lt + 1 < tn) {
      size_t zo = zoff0 + (size_t)(lt + 1) * 8192;
#pragma unroll
      for (int j = 0; j < 8; ++j)
        z0[j] = *(const i32x4*)(zxq + zo + (size_t)(wv * 8 + j) * 128);
    }

    // write z to LDS: real rows 0..7 live in lanes l4<2 (conflict-free b32)
    if (l4 < 2) {
#pragma unroll
      for (int j = 0; j < 8; ++j) {
        int col = (wv * 8 + j) * 16 + l15;
#pragma unroll
        for (int i = 0; i < 4; ++i)
          zl[(l4 * 4 + i) * 1024 + col] = acc[j][i];
      }
    }
    __syncthreads();

    // gates: thread owns (unit u, 4 batches); dequant, activate, re-quant h
#pragma unroll
    for (int i = 0; i < 4; ++i) {
      int b = bg * 4 + i;
      float zi = (float)zl[b * 1024 +       u] * dqv[0] + bhv[0];
      float zf = (float)zl[b * 1024 + 256 + u] * dqv[1] + bhv[1];
      float zg = (float)zl[b * 1024 + 512 + u] * dqv[2] + bhv[2];
      float zo = (float)zl[b * 1024 + 768 + u] * dqv[3] + bhv[3];
      c[i] = sigf(zf) * c[i] + sigf(zi) * tanh_fast(zg);
      float h = sigf(zo) * tanh_fast(c[i]);
      aF[kqu * 1024 + (b | (lgu << 4)) * 16 + iiu] =
          (signed char)(int)rintf(h * 127.f);
      if (lt == tn - 1) hst[(p * 8 + b) * 256 + u] = h;
    }
    __syncthreads();
  }

#pragma unroll
  for (int i = 0; i < 4; ++i)
    cst[(p * 8 + bg * 4 + i) * 256 + u] = c[i];
}

// ---------------- y = h @ Wo + bo ----------------
__global__ __launch_bounds__(64) void k_out(const float* __restrict__ hfin,
                                            const float* __restrict__ wo,
                                            const float* __restrict__ bo,
                                            float* __restrict__ y) {
  __shared__ float hsm[256];
  int b = blockIdx.x, tid = threadIdx.x;
  for (int i = tid; i < 256; i += 64) hsm[i] = hfin[b * 256 + i];
  __syncthreads();
  if (tid < NCLS) {
    float s = bo[tid];
    for (int k = 0; k < 256; ++k) s += hsm[k] * wo[k * NCLS + tid];
    y[b * NCLS + tid] = s;
  }
}

// ---------------- launcher ----------------
extern "C" void kernel_launch(void* const* d_in, const int* in_sizes, int n_in,
                              void* d_out, int out_size, void* d_ws, size_t ws_size,
                              hipStream_t stream) {
  const int*   tokens = (const int*)d_in[0];
  const float* embed  = (const float*)d_in[3];
  const float* wi     = (const float*)d_in[4];
  const float* wh     = (const float*)d_in[5];
  const float* bh     = (const float*)d_in[6];
  const float* wo     = (const float*)d_in[7];
  const float* bo     = (const float*)d_in[8];
  float* y = (float*)d_out;

  char* ws = (char*)d_ws;
  bf16* eb        = (bf16*)ws;        ws += (size_t)NV * ND * 2;    // 16.38 MB
  bf16* wit       = (bf16*)ws;        ws += (size_t)NH4 * ND * 2;   // 0.5 MB
  signed char* whq = (signed char*)ws; ws += (size_t)ND * NH4;      // 0.25 MB
  float* dqv      = (float*)ws;       ws += (size_t)NH4 * 4;        // 4 KB
  float* rdq      = (float*)ws;       ws += (size_t)NH4 * 4;        // 4 KB
  float* rw       = (float*)ws;       ws += (size_t)NH4 * 4;        // 4 KB
  float* cst      = (float*)ws;       ws += (size_t)NB * ND * 4;    // 64 KB
  float* hst      = (float*)ws;       ws += (size_t)NB * ND * 4;    // 64 KB
  size_t fixed = (size_t)(ws - (char*)d_ws);

  // zxq (i32): CH steps x 64 batches x 1024 cols x 4 B = CH x 256 KB
  int CHUNK = 32, lgch = 5;
  static const int cand[]  = {512, 256, 128, 64, 32};
  static const int candl[] = {9, 8, 7, 6, 5};
  for (int ci = 0; ci < 5; ++ci) {
    size_t need = fixed + (size_t)cand[ci] * 262144;
    if (need <= ws_size) { CHUNK = cand[ci]; lgch = candl[ci]; break; }
  }
  int* zxq = (int*)ws;

  hipLaunchKernelGGL(k_cvt_embed, dim3(NV * ND / 4 / 256), dim3(256), 0, stream, embed, eb);
  hipLaunchKernelGGL(k_cvt_wi,    dim3(NH4 * ND / 256), dim3(256), 0, stream, wi, wit);
  hipLaunchKernelGGL(k_scale,     dim3(4), dim3(256), 0, stream, wh, dqv, rdq, rw);
  hipLaunchKernelGGL(k_cvt_whq,   dim3(1024), dim3(256), 0, stream, wh, rw, whq);

  for (int t0 = 0; t0 < NT; t0 += CHUNK) {
    hipLaunchKernelGGL(k_gemm_zx, dim3(CHUNK * 16), dim3(256), 0, stream,
                       tokens, eb, wit, rdq, zxq, t0, lgch);
    hipLaunchKernelGGL(k_lstm, dim3(8), dim3(512), 0, stream,
                       zxq, whq, dqv, bh, cst, hst, t0, CHUNK, lgch);
  }
  hipLaunchKernelGGL(k_out, dim3(NB), dim3(64), 0, stream, hst, wo, bo, y);
}

// Round 12
// 2319.237 us; speedup vs baseline: 2.0008x; 1.4970x over previous
//
#include <hip/hip_runtime.h>
#include <hip/hip_bf16.h>
#include <stdint.h>

typedef __hip_bfloat16 bf16;
typedef __attribute__((ext_vector_type(8))) short short8;
typedef __attribute__((ext_vector_type(4))) float f32x4;
typedef __attribute__((ext_vector_type(4))) int i32x4;
typedef __attribute__((ext_vector_type(2))) int i32x2;
typedef __attribute__((ext_vector_type(4))) unsigned int u32x4;

#define NB   64
#define NT   2048
#define NV   32000
#define ND   256
#define NH4  1024
#define NCLS 27

// ---------------- dtype conversion / packing ----------------

__global__ __launch_bounds__(256) void k_cvt_embed(const float* __restrict__ e,
                                                   bf16* __restrict__ o) {
  int i = blockIdx.x * blockDim.x + threadIdx.x;
  float4 v = reinterpret_cast<const float4*>(e)[i];
  union { bf16 h[4]; uint2 u; } pk;
  pk.h[0] = __float2bfloat16(v.x);
  pk.h[1] = __float2bfloat16(v.y);
  pk.h[2] = __float2bfloat16(v.z);
  pk.h[3] = __float2bfloat16(v.w);
  reinterpret_cast<uint2*>(o)[i] = pk.u;
}

// Wi [256][1024] f32 -> Wi_t [1024][256] bf16
__global__ __launch_bounds__(256) void k_cvt_wi(const float* __restrict__ wi,
                                                bf16* __restrict__ wit) {
  int i = blockIdx.x * blockDim.x + threadIdx.x;
  int col = i >> 8;
  int k   = i & 255;
  wit[i] = __float2bfloat16(wi[k * NH4 + col]);
}

// per-column scales for i8 quantization of Wh.
__global__ __launch_bounds__(256) void k_scale(const float* __restrict__ wh,
                                               float* __restrict__ dq,
                                               float* __restrict__ rdq,
                                               float* __restrict__ rw) {
  int col = blockIdx.x * 256 + threadIdx.x;   // grid 4
  float m = 0.f;
  for (int k = 0; k < ND; ++k) m = fmaxf(m, fabsf(wh[k * NH4 + col]));
  dq[col]  = m * (1.f / 16129.f);
  rdq[col] = 16129.f / m;
  rw[col]  = 127.f / m;
}

// Wh -> i8 B-fragments for mfma_i32_16x16x64_i8
__global__ __launch_bounds__(256) void k_cvt_whq(const float* __restrict__ wh,
                                                 const float* __restrict__ rw,
                                                 signed char* __restrict__ whq) {
  int idx  = blockIdx.x * 256 + threadIdx.x;  // grid 1024
  int ii   = idx & 15;
  int lane = (idx >> 4) & 63;
  int kq   = (idx >> 10) & 3;
  int nt   = idx >> 12;
  int k   = kq * 64 + (lane >> 4) * 16 + ii;
  int col = nt * 16 + (lane & 15);
  whq[idx] = (signed char)(int)rintf(wh[k * NH4 + col] * rw[col]);
}

// ---------------- zx = embed[tokens] @ Wi, i32 dot-grid, 2-row C-slices ----------------
// dword slot for (b, lt, col): ((p<<lgch)+lt)*2048 + nt*32 + (col&15)*2 + (b&1)
// where p=b>>1, nt=col>>4 — i.e. per (p,lt) an 8KB block that IS the C-operand
// fragment set (lane=col&15, regs 0..1 = batches 2p,2p+1) of the scan's MFMAs.
__global__ __launch_bounds__(256) void k_gemm_zx(const int*  __restrict__ tokens,
                                                 const bf16* __restrict__ eb,
                                                 const bf16* __restrict__ wit,
                                                 const float* __restrict__ rdq,
                                                 int* __restrict__ zxq,
                                                 int t0, int lgch) {
  __shared__ bf16 As[4 * 64 * 8];
  __shared__ bf16 Bs[4 * 64 * 8];
  int bid  = blockIdx.x;
  int nb   = bid & 15;
  int mb   = bid >> 4;          // step within chunk
  int n0   = nb * 64;
  int tid  = threadIdx.x, lane = tid & 63, wave = tid >> 6;
  int wm   = wave >> 1, wn = wave & 1;
  int srow = tid >> 2;          // batch 0..63
  int skg  = tid & 3;

  long trow = (long)tokens[srow * NT + t0 + mb] * ND;
  const bf16* ap = eb  + trow + skg * 8;
  const bf16* bp = wit + (long)(n0 + srow) * ND + skg * 8;
  bf16* as_dst = &As[(skg * 64 + srow) * 8];
  bf16* bs_dst = &Bs[(skg * 64 + srow) * 8];

  f32x4 acc[2][2] = {};
  for (int k0 = 0; k0 < ND; k0 += 32) {
    __syncthreads();
    *(u32x4*)as_dst = *(const u32x4*)(ap + k0);
    *(u32x4*)bs_dst = *(const u32x4*)(bp + k0);
    __syncthreads();
    short8 a0 = *(const short8*)&As[((lane >> 4) * 64 + wm * 32 +  0 + (lane & 15)) * 8];
    short8 a1 = *(const short8*)&As[((lane >> 4) * 64 + wm * 32 + 16 + (lane & 15)) * 8];
    short8 b0 = *(const short8*)&Bs[((lane >> 4) * 64 + wn * 32 +  0 + (lane & 15)) * 8];
    short8 b1 = *(const short8*)&Bs[((lane >> 4) * 64 + wn * 32 + 16 + (lane & 15)) * 8];
    acc[0][0] = __builtin_amdgcn_mfma_f32_16x16x32_bf16(a0, b0, acc[0][0], 0, 0, 0);
    acc[0][1] = __builtin_amdgcn_mfma_f32_16x16x32_bf16(a0, b1, acc[0][1], 0, 0, 0);
    acc[1][0] = __builtin_amdgcn_mfma_f32_16x16x32_bf16(a1, b0, acc[1][0], 0, 0, 0);
    acc[1][1] = __builtin_amdgcn_mfma_f32_16x16x32_bf16(a1, b1, acc[1][1], 0, 0, 0);
  }

  int cb  = n0 + wn * 32 + (lane & 15);
  float rq0 = rdq[cb], rq1 = rdq[cb + 16];
  int bb = wm * 32 + (lane >> 4) * 4;         // batch base (multiple of 4)
#pragma unroll
  for (int fm = 0; fm < 2; ++fm) {
    int b0r = bb + fm * 16;                   // even
    int p0  = b0r >> 1;
#pragma unroll
    for (int fn = 0; fn < 2; ++fn) {
      int col = cb + fn * 16;
      int nt  = col >> 4;
      float rq = fn ? rq1 : rq0;
      int v0 = (int)rintf(acc[fm][fn][0] * rq);
      int v1 = (int)rintf(acc[fm][fn][1] * rq);
      int v2 = (int)rintf(acc[fm][fn][2] * rq);
      int v3 = (int)rintf(acc[fm][fn][3] * rq);
      size_t base = ((size_t)(p0 << lgch) + mb) * 2048 + nt * 32 + (col & 15) * 2;
      i32x2 w01; w01[0] = v0; w01[1] = v1;
      i32x2 w23; w23[0] = v2; w23[1] = v3;
      *(i32x2*)(zxq + base) = w01;
      *(i32x2*)(zxq + base + ((size_t)1 << lgch) * 2048) = w23;
    }
  }
}

// ---------------- LSTM scan: fully CU-local, i8 MFMA, 32 WGs ----------------
// 32 WGs x 512 threads (8 waves, 1 WG/CU). WG p owns batches {2p, 2p+1} x ALL
// 256 units -> no inter-WG communication. Wh fully register-resident as i8
// (w[8][4] = 128 VGPR/wave). A rows 2..15 are zero padding; C preloaded with
// scaled zx in rows 0..1 (pad-row outputs never read). 2 barriers/step.
// Gate phase: exactly ONE cell (batch b, unit u) per thread.
__device__ __forceinline__ float sigf(float x) {
  return __builtin_amdgcn_rcpf(1.f + __expf(-x));
}
__device__ __forceinline__ float tanh_fast(float x) {
  return 1.f - 2.f * __builtin_amdgcn_rcpf(1.f + __expf(2.f * x));
}

__global__ __launch_bounds__(512, 1) void k_lstm(const int* __restrict__ zxq,
                                                 const signed char* __restrict__ whq,
                                                 const float* __restrict__ dq,
                                                 const float* __restrict__ bh,
                                                 float* __restrict__ cst,
                                                 float* __restrict__ hst,
                                                 int t0, int tn, int lgch) {
  __shared__ int  zl[2 * 1024];            // [b][col] i32, 8 KB
  __shared__ signed char aF[4 * 64 * 16];  // [kq][la][16] i8 A-frags, 4 KB

  int p   = blockIdx.x;        // batches {2p, 2p+1}
  int tid = threadIdx.x;
  int l   = tid & 63;
  int wv  = tid >> 6;
  int l15 = l & 15, l4 = l >> 4;
  int u   = tid & 255;         // gate-phase unit
  int b   = tid >> 8;          // gate-phase batch 0/1

  // register-resident Wh i8 B-fragments (static indices only)
  i32x4 w[8][4];
#pragma unroll
  for (int j = 0; j < 8; ++j) {
    int nt = wv * 8 + j;
#pragma unroll
    for (int kq = 0; kq < 4; ++kq)
      w[j][kq] = *(const i32x4*)&whq[((nt * 4 + kq) * 64 + l) * 16];
  }
#pragma unroll
  for (int j = 0; j < 8; ++j)
#pragma unroll
    for (int kq = 0; kq < 4; ++kq)
      asm volatile("" : "+v"(w[j][kq]));

  float dqv[4], bhv[4];
#pragma unroll
  for (int q = 0; q < 4; ++q) { dqv[q] = dq[q * 256 + u]; bhv[q] = bh[q * 256 + u]; }
  float c = (t0 == 0) ? 0.f : cst[(p * 2 + b) * 256 + u];

  int kqu = u >> 6, lgu = (u >> 4) & 3, iiu = u & 15;

  // zero A-frag LDS (pad rows 2..15 stay zero forever)
  if (tid < 256) ((i32x4*)aF)[tid] = (i32x4)0;
  __syncthreads();
  if (t0 != 0) {
    int hq = (int)rintf(hst[(p * 2 + b) * 256 + u] * 127.f);
    aF[kqu * 1024 + (b | (lgu << 4)) * 16 + iiu] = (signed char)hq;
  }
  __syncthreads();

  // per-lane zx base (lane15 slot); step 0 preload
  const int* zb = zxq + ((size_t)(p << lgch)) * 2048 + l15 * 2;
  i32x2 z0[8];
#pragma unroll
  for (int j = 0; j < 8; ++j)
    z0[j] = *(const i32x2*)(zb + (wv * 8 + j) * 32);

  for (int lt = 0; lt < tn; ++lt) {
    // A-fragments from LDS
    i32x4 a0 = *(const i32x4*)&aF[0 * 1024 + l * 16];
    i32x4 a1 = *(const i32x4*)&aF[1 * 1024 + l * 16];
    i32x4 a2 = *(const i32x4*)&aF[2 * 1024 + l * 16];
    i32x4 a3 = *(const i32x4*)&aF[3 * 1024 + l * 16];

    // z = zx + h @ Wh (i32 dot; C rows 0..1 preloaded with scaled zx)
    i32x4 acc[8];
#pragma unroll
    for (int j = 0; j < 8; ++j) {
      i32x4 zc; zc[0] = z0[j][0]; zc[1] = z0[j][1]; zc[2] = 0; zc[3] = 0;
      i32x4 t;
      t = __builtin_amdgcn_mfma_i32_16x16x64_i8(a0, w[j][0], zc, 0, 0, 0);
      t = __builtin_amdgcn_mfma_i32_16x16x64_i8(a1, w[j][1], t, 0, 0, 0);
      t = __builtin_amdgcn_mfma_i32_16x16x64_i8(a2, w[j][2], t, 0, 0, 0);
      acc[j] = __builtin_amdgcn_mfma_i32_16x16x64_i8(a3, w[j][3], t, 0, 0, 0);
    }

    // prefetch next step's zx (z0 dead after C-construct above)
    if (lt + 1 < tn) {
      const int* zn = zb + (size_t)(lt + 1) * 2048;
#pragma unroll
      for (int j = 0; j < 8; ++j)
        z0[j] = *(const i32x2*)(zn + (wv * 8 + j) * 32);
    }

    // write real rows 0..1 to LDS (lanes 0..15 hold them in regs 0..1)
    if (l4 == 0) {
#pragma unroll
      for (int j = 0; j < 8; ++j) {
        int col = (wv * 8 + j) * 16 + l15;
        zl[col]        = acc[j][0];
        zl[1024 + col] = acc[j][1];
      }
    }
    __syncthreads();

    // gates: ONE cell (b, u) per thread
    {
      float zi = (float)zl[b * 1024 +       u] * dqv[0] + bhv[0];
      float zf = (float)zl[b * 1024 + 256 + u] * dqv[1] + bhv[1];
      float zg = (float)zl[b * 1024 + 512 + u] * dqv[2] + bhv[2];
      float zo = (float)zl[b * 1024 + 768 + u] * dqv[3] + bhv[3];
      c = sigf(zf) * c + sigf(zi) * tanh_fast(zg);
      float h = sigf(zo) * tanh_fast(c);
      aF[kqu * 1024 + (b | (lgu << 4)) * 16 + iiu] =
          (signed char)(int)rintf(h * 127.f);
      if (lt == tn - 1) hst[(p * 2 + b) * 256 + u] = h;
    }
    __syncthreads();
  }

  cst[(p * 2 + b) * 256 + u] = c;
}

// ---------------- y = h @ Wo + bo ----------------
__global__ __launch_bounds__(64) void k_out(const float* __restrict__ hfin,
                                            const float* __restrict__ wo,
                                            const float* __restrict__ bo,
                                            float* __restrict__ y) {
  __shared__ float hsm[256];
  int b = blockIdx.x, tid = threadIdx.x;
  for (int i = tid; i < 256; i += 64) hsm[i] = hfin[b * 256 + i];
  __syncthreads();
  if (tid < NCLS) {
    float s = bo[tid];
    for (int k = 0; k < 256; ++k) s += hsm[k] * wo[k * NCLS + tid];
    y[b * NCLS + tid] = s;
  }
}

// ---------------- launcher ----------------
extern "C" void kernel_launch(void* const* d_in, const int* in_sizes, int n_in,
                              void* d_out, int out_size, void* d_ws, size_t ws_size,
                              hipStream_t stream) {
  const int*   tokens = (const int*)d_in[0];
  const float* embed  = (const float*)d_in[3];
  const float* wi     = (const float*)d_in[4];
  const float* wh     = (const float*)d_in[5];
  const float* bh     = (const float*)d_in[6];
  const float* wo     = (const float*)d_in[7];
  const float* bo     = (const float*)d_in[8];
  float* y = (float*)d_out;

  char* ws = (char*)d_ws;
  bf16* eb        = (bf16*)ws;        ws += (size_t)NV * ND * 2;    // 16.38 MB
  bf16* wit       = (bf16*)ws;        ws += (size_t)NH4 * ND * 2;   // 0.5 MB
  signed char* whq = (signed char*)ws; ws += (size_t)ND * NH4;      // 0.25 MB
  float* dqv      = (float*)ws;       ws += (size_t)NH4 * 4;        // 4 KB
  float* rdq      = (float*)ws;       ws += (size_t)NH4 * 4;        // 4 KB
  float* rw       = (float*)ws;       ws += (size_t)NH4 * 4;        // 4 KB
  float* cst      = (float*)ws;       ws += (size_t)NB * ND * 4;    // 64 KB
  float* hst      = (float*)ws;       ws += (size_t)NB * ND * 4;    // 64 KB
  size_t fixed = (size_t)(ws - (char*)d_ws);

  // zxq (i32): CH steps x 32 p-groups x 8KB = CH x 256 KB
  int CHUNK = 32, lgch = 5;
  static const int cand[]  = {512, 256, 128, 64, 32};
  static const int candl[] = {9, 8, 7, 6, 5};
  for (int ci = 0; ci < 5; ++ci) {
    size_t need = fixed + (size_t)cand[ci] * 262144;
    if (need <= ws_size) { CHUNK = cand[ci]; lgch = candl[ci]; break; }
  }
  int* zxq = (int*)ws;

  hipLaunchKernelGGL(k_cvt_embed, dim3(NV * ND / 4 / 256), dim3(256), 0, stream, embed, eb);
  hipLaunchKernelGGL(k_cvt_wi,    dim3(NH4 * ND / 256), dim3(256), 0, stream, wi, wit);
  hipLaunchKernelGGL(k_scale,     dim3(4), dim3(256), 0, stream, wh, dqv, rdq, rw);
  hipLaunchKernelGGL(k_cvt_whq,   dim3(1024), dim3(256), 0, stream, wh, rw, whq);

  for (int t0 = 0; t0 < NT; t0 += CHUNK) {
    hipLaunchKernelGGL(k_gemm_zx, dim3(CHUNK * 16), dim3(256), 0, stream,
                       tokens, eb, wit, rdq, zxq, t0, lgch);
    hipLaunchKernelGGL(k_lstm, dim3(32), dim3(512), 0, stream,
                       zxq, whq, dqv, bh, cst, hst, t0, CHUNK, lgch);
  }
  hipLaunchKernelGGL(k_out, dim3(NB), dim3(64), 0, stream, hst, wo, bo, y);
}

// Round 13
// 2281.113 us; speedup vs baseline: 2.0342x; 1.0167x over previous
//
#include <hip/hip_runtime.h>
#include <hip/hip_bf16.h>
#include <stdint.h>

typedef __hip_bfloat16 bf16;
typedef __attribute__((ext_vector_type(8))) short short8;
typedef __attribute__((ext_vector_type(4))) float f32x4;
typedef __attribute__((ext_vector_type(4))) int i32x4;
typedef __attribute__((ext_vector_type(2))) int i32x2;
typedef __attribute__((ext_vector_type(4))) unsigned int u32x4;

#define NB   64
#define NT   2048
#define NV   32000
#define ND   256
#define NH4  1024
#define NCLS 27

// ---------------- dtype conversion / packing ----------------

__global__ __launch_bounds__(256) void k_cvt_embed(const float* __restrict__ e,
                                                   bf16* __restrict__ o) {
  int i = blockIdx.x * blockDim.x + threadIdx.x;
  float4 v = reinterpret_cast<const float4*>(e)[i];
  union { bf16 h[4]; uint2 u; } pk;
  pk.h[0] = __float2bfloat16(v.x);
  pk.h[1] = __float2bfloat16(v.y);
  pk.h[2] = __float2bfloat16(v.z);
  pk.h[3] = __float2bfloat16(v.w);
  reinterpret_cast<uint2*>(o)[i] = pk.u;
}

// Wi [256][1024] f32 -> Wi_t [1024][256] bf16
__global__ __launch_bounds__(256) void k_cvt_wi(const float* __restrict__ wi,
                                                bf16* __restrict__ wit) {
  int i = blockIdx.x * blockDim.x + threadIdx.x;
  int col = i >> 8;
  int k   = i & 255;
  wit[i] = __float2bfloat16(wi[k * NH4 + col]);
}

// per-column scales for i8 quantization of Wh.
__global__ __launch_bounds__(256) void k_scale(const float* __restrict__ wh,
                                               float* __restrict__ dq,
                                               float* __restrict__ rdq,
                                               float* __restrict__ rw) {
  int col = blockIdx.x * 256 + threadIdx.x;   // grid 4
  float m = 0.f;
  for (int k = 0; k < ND; ++k) m = fmaxf(m, fabsf(wh[k * NH4 + col]));
  dq[col]  = m * (1.f / 16129.f);
  rdq[col] = 16129.f / m;
  rw[col]  = 127.f / m;
}

// Wh -> i8 B-fragments for mfma_i32_16x16x64_i8
__global__ __launch_bounds__(256) void k_cvt_whq(const float* __restrict__ wh,
                                                 const float* __restrict__ rw,
                                                 signed char* __restrict__ whq) {
  int idx  = blockIdx.x * 256 + threadIdx.x;  // grid 1024
  int ii   = idx & 15;
  int lane = (idx >> 4) & 63;
  int kq   = (idx >> 10) & 3;
  int nt   = idx >> 12;
  int k   = kq * 64 + (lane >> 4) * 16 + ii;
  int col = nt * 16 + (lane & 15);
  whq[idx] = (signed char)(int)rintf(wh[k * NH4 + col] * rw[col]);
}

// ---------------- zx = embed[tokens] @ Wi, i32 dot-grid, 2-row C-slices ----------------
// dword slot for (b, lt, col): ((p<<lgch)+lt)*2048 + nt*32 + (col&15)*2 + (b&1)
__global__ __launch_bounds__(256) void k_gemm_zx(const int*  __restrict__ tokens,
                                                 const bf16* __restrict__ eb,
                                                 const bf16* __restrict__ wit,
                                                 const float* __restrict__ rdq,
                                                 int* __restrict__ zxq,
                                                 int t0, int lgch) {
  __shared__ bf16 As[4 * 64 * 8];
  __shared__ bf16 Bs[4 * 64 * 8];
  int bid  = blockIdx.x;
  int nb   = bid & 15;
  int mb   = bid >> 4;          // step within chunk
  int n0   = nb * 64;
  int tid  = threadIdx.x, lane = tid & 63, wave = tid >> 6;
  int wm   = wave >> 1, wn = wave & 1;
  int srow = tid >> 2;          // batch 0..63
  int skg  = tid & 3;

  long trow = (long)tokens[srow * NT + t0 + mb] * ND;
  const bf16* ap = eb  + trow + skg * 8;
  const bf16* bp = wit + (long)(n0 + srow) * ND + skg * 8;
  bf16* as_dst = &As[(skg * 64 + srow) * 8];
  bf16* bs_dst = &Bs[(skg * 64 + srow) * 8];

  f32x4 acc[2][2] = {};
  for (int k0 = 0; k0 < ND; k0 += 32) {
    __syncthreads();
    *(u32x4*)as_dst = *(const u32x4*)(ap + k0);
    *(u32x4*)bs_dst = *(const u32x4*)(bp + k0);
    __syncthreads();
    short8 a0 = *(const short8*)&As[((lane >> 4) * 64 + wm * 32 +  0 + (lane & 15)) * 8];
    short8 a1 = *(const short8*)&As[((lane >> 4) * 64 + wm * 32 + 16 + (lane & 15)) * 8];
    short8 b0 = *(const short8*)&Bs[((lane >> 4) * 64 + wn * 32 +  0 + (lane & 15)) * 8];
    short8 b1 = *(const short8*)&Bs[((lane >> 4) * 64 + wn * 32 + 16 + (lane & 15)) * 8];
    acc[0][0] = __builtin_amdgcn_mfma_f32_16x16x32_bf16(a0, b0, acc[0][0], 0, 0, 0);
    acc[0][1] = __builtin_amdgcn_mfma_f32_16x16x32_bf16(a0, b1, acc[0][1], 0, 0, 0);
    acc[1][0] = __builtin_amdgcn_mfma_f32_16x16x32_bf16(a1, b0, acc[1][0], 0, 0, 0);
    acc[1][1] = __builtin_amdgcn_mfma_f32_16x16x32_bf16(a1, b1, acc[1][1], 0, 0, 0);
  }

  int cb  = n0 + wn * 32 + (lane & 15);
  float rq0 = rdq[cb], rq1 = rdq[cb + 16];
  int bb = wm * 32 + (lane >> 4) * 4;         // batch base (multiple of 4)
#pragma unroll
  for (int fm = 0; fm < 2; ++fm) {
    int b0r = bb + fm * 16;                   // even
    int p0  = b0r >> 1;
#pragma unroll
    for (int fn = 0; fn < 2; ++fn) {
      int col = cb + fn * 16;
      int nt  = col >> 4;
      float rq = fn ? rq1 : rq0;
      int v0 = (int)rintf(acc[fm][fn][0] * rq);
      int v1 = (int)rintf(acc[fm][fn][1] * rq);
      int v2 = (int)rintf(acc[fm][fn][2] * rq);
      int v3 = (int)rintf(acc[fm][fn][3] * rq);
      size_t base = ((size_t)(p0 << lgch) + mb) * 2048 + nt * 32 + (col & 15) * 2;
      i32x2 w01; w01[0] = v0; w01[1] = v1;
      i32x2 w23; w23[0] = v2; w23[1] = v3;
      *(i32x2*)(zxq + base) = w01;
      *(i32x2*)(zxq + base + ((size_t)1 << lgch) * 2048) = w23;
    }
  }
}

// ---------------- LSTM scan: fully CU-local, i8 MFMA, 32 WGs ----------------
// 32 WGs x 512 threads (8 waves, 1 WG/CU). WG p owns batches {2p, 2p+1} x ALL
// 256 units -> no inter-WG communication. Wh register-resident as i8
// (w[8][4] = 128 regs/wave). A rows 2..15 zero padding; C preloaded with
// scaled zx rows 0..1. R13: depth-2 zx prefetch (zA/zB, loop unrolled x2 --
// covers L3/HBM latency ~2 steps ahead) + transposed z-LDS [b][u*4+q] so the
// gate phase reads its 4 gates with ONE ds_read_b128.
__device__ __forceinline__ float sigf(float x) {
  return __builtin_amdgcn_rcpf(1.f + __expf(-x));
}
__device__ __forceinline__ float tanh_fast(float x) {
  return 1.f - 2.f * __builtin_amdgcn_rcpf(1.f + __expf(2.f * x));
}

#define LSTM_STEP(Z, ST)                                                        \
  {                                                                             \
    i32x4 a0 = *(const i32x4*)&aF[0 * 1024 + l * 16];                           \
    i32x4 a1 = *(const i32x4*)&aF[1 * 1024 + l * 16];                           \
    i32x4 a2 = *(const i32x4*)&aF[2 * 1024 + l * 16];                           \
    i32x4 a3 = *(const i32x4*)&aF[3 * 1024 + l * 16];                           \
    i32x4 acc[8];                                                               \
    _Pragma("unroll")                                                           \
    for (int j = 0; j < 8; ++j) {                                               \
      i32x4 zc; zc[0] = Z[j][0]; zc[1] = Z[j][1]; zc[2] = 0; zc[3] = 0;         \
      i32x4 t;                                                                  \
      t = __builtin_amdgcn_mfma_i32_16x16x64_i8(a0, w[j][0], zc, 0, 0, 0);      \
      t = __builtin_amdgcn_mfma_i32_16x16x64_i8(a1, w[j][1], t, 0, 0, 0);       \
      t = __builtin_amdgcn_mfma_i32_16x16x64_i8(a2, w[j][2], t, 0, 0, 0);       \
      acc[j] = __builtin_amdgcn_mfma_i32_16x16x64_i8(a3, w[j][3], t, 0, 0, 0);  \
    }                                                                           \
    if ((ST) + 2 < tn) {                                                        \
      const int* zn = zb + (size_t)((ST) + 2) * 2048;                           \
      _Pragma("unroll")                                                         \
      for (int j = 0; j < 8; ++j)                                               \
        Z[j] = *(const i32x2*)(zn + (wv * 8 + j) * 32);                         \
    }                                                                           \
    if (l4 == 0) {                                                              \
      _Pragma("unroll")                                                         \
      for (int j = 0; j < 8; ++j) {                                             \
        int col = (wv * 8 + j) * 16 + l15;                                      \
        int tt  = ((col & 255) << 2) | (col >> 8);                              \
        zl[tt]        = acc[j][0];                                              \
        zl[1024 + tt] = acc[j][1];                                              \
      }                                                                         \
    }                                                                           \
    __syncthreads();                                                            \
    {                                                                           \
      i32x4 zr = *(const i32x4*)&zl[b * 1024 + u * 4];                          \
      float zi = (float)zr[0] * dqv[0] + bhv[0];                                \
      float zf = (float)zr[1] * dqv[1] + bhv[1];                                \
      float zg = (float)zr[2] * dqv[2] + bhv[2];                                \
      float zo = (float)zr[3] * dqv[3] + bhv[3];                                \
      c = sigf(zf) * c + sigf(zi) * tanh_fast(zg);                              \
      float h = sigf(zo) * tanh_fast(c);                                        \
      aF[kqu * 1024 + (b | (lgu << 4)) * 16 + iiu] =                            \
          (signed char)(int)rintf(h * 127.f);                                   \
      if ((ST) == tn - 1) hst[(p * 2 + b) * 256 + u] = h;                       \
    }                                                                           \
    __syncthreads();                                                            \
  }

__global__ __launch_bounds__(512, 1) void k_lstm(const int* __restrict__ zxq,
                                                 const signed char* __restrict__ whq,
                                                 const float* __restrict__ dq,
                                                 const float* __restrict__ bh,
                                                 float* __restrict__ cst,
                                                 float* __restrict__ hst,
                                                 int t0, int tn, int lgch) {
  __shared__ int  zl[2 * 1024];            // [b][u*4+q] i32 (transposed), 8 KB
  __shared__ signed char aF[4 * 64 * 16];  // [kq][la][16] i8 A-frags, 4 KB

  int p   = blockIdx.x;        // batches {2p, 2p+1}
  int tid = threadIdx.x;
  int l   = tid & 63;
  int wv  = tid >> 6;
  int l15 = l & 15, l4 = l >> 4;
  int u   = tid & 255;         // gate-phase unit
  int b   = tid >> 8;          // gate-phase batch 0/1

  // register-resident Wh i8 B-fragments (static indices only)
  i32x4 w[8][4];
#pragma unroll
  for (int j = 0; j < 8; ++j) {
    int nt = wv * 8 + j;
#pragma unroll
    for (int kq = 0; kq < 4; ++kq)
      w[j][kq] = *(const i32x4*)&whq[((nt * 4 + kq) * 64 + l) * 16];
  }
#pragma unroll
  for (int j = 0; j < 8; ++j)
#pragma unroll
    for (int kq = 0; kq < 4; ++kq)
      asm volatile("" : "+v"(w[j][kq]));

  float dqv[4], bhv[4];
#pragma unroll
  for (int q = 0; q < 4; ++q) { dqv[q] = dq[q * 256 + u]; bhv[q] = bh[q * 256 + u]; }
  float c = (t0 == 0) ? 0.f : cst[(p * 2 + b) * 256 + u];

  int kqu = u >> 6, lgu = (u >> 4) & 3, iiu = u & 15;

  // zero A-frag LDS (pad rows 2..15 stay zero forever)
  if (tid < 256) ((i32x4*)aF)[tid] = (i32x4)0;
  __syncthreads();
  if (t0 != 0) {
    int hq = (int)rintf(hst[(p * 2 + b) * 256 + u] * 127.f);
    aF[kqu * 1024 + (b | (lgu << 4)) * 16 + iiu] = (signed char)hq;
  }
  __syncthreads();

  // per-lane zx base; depth-2 preload (steps 0 and 1)
  const int* zb = zxq + ((size_t)(p << lgch)) * 2048 + l15 * 2;
  i32x2 zA[8], zB[8];
#pragma unroll
  for (int j = 0; j < 8; ++j) {
    zA[j] = *(const i32x2*)(zb + (wv * 8 + j) * 32);
    zB[j] = *(const i32x2*)(zb + 2048 + (wv * 8 + j) * 32);
  }

  for (int lt = 0; lt < tn; lt += 2) {
    LSTM_STEP(zA, lt)
    LSTM_STEP(zB, lt + 1)
  }

  cst[(p * 2 + b) * 256 + u] = c;
}

// ---------------- y = h @ Wo + bo ----------------
__global__ __launch_bounds__(64) void k_out(const float* __restrict__ hfin,
                                            const float* __restrict__ wo,
                                            const float* __restrict__ bo,
                                            float* __restrict__ y) {
  __shared__ float hsm[256];
  int b = blockIdx.x, tid = threadIdx.x;
  for (int i = tid; i < 256; i += 64) hsm[i] = hfin[b * 256 + i];
  __syncthreads();
  if (tid < NCLS) {
    float s = bo[tid];
    for (int k = 0; k < 256; ++k) s += hsm[k] * wo[k * NCLS + tid];
    y[b * NCLS + tid] = s;
  }
}

// ---------------- launcher ----------------
extern "C" void kernel_launch(void* const* d_in, const int* in_sizes, int n_in,
                              void* d_out, int out_size, void* d_ws, size_t ws_size,
                              hipStream_t stream) {
  const int*   tokens = (const int*)d_in[0];
  const float* embed  = (const float*)d_in[3];
  const float* wi     = (const float*)d_in[4];
  const float* wh     = (const float*)d_in[5];
  const float* bh     = (const float*)d_in[6];
  const float* wo     = (const float*)d_in[7];
  const float* bo     = (const float*)d_in[8];
  float* y = (float*)d_out;

  char* ws = (char*)d_ws;
  bf16* eb        = (bf16*)ws;        ws += (size_t)NV * ND * 2;    // 16.38 MB
  bf16* wit       = (bf16*)ws;        ws += (size_t)NH4 * ND * 2;   // 0.5 MB
  signed char* whq = (signed char*)ws; ws += (size_t)ND * NH4;      // 0.25 MB
  float* dqv      = (float*)ws;       ws += (size_t)NH4 * 4;        // 4 KB
  float* rdq      = (float*)ws;       ws += (size_t)NH4 * 4;        // 4 KB
  float* rw       = (float*)ws;       ws += (size_t)NH4 * 4;        // 4 KB
  float* cst      = (float*)ws;       ws += (size_t)NB * ND * 4;    // 64 KB
  float* hst      = (float*)ws;       ws += (size_t)NB * ND * 4;    // 64 KB
  size_t fixed = (size_t)(ws - (char*)d_ws);

  // zxq (i32): CH steps x 32 p-groups x 8KB = CH x 256 KB
  int CHUNK = 32, lgch = 5;
  static const int cand[]  = {512, 256, 128, 64, 32};
  static const int candl[] = {9, 8, 7, 6, 5};
  for (int ci = 0; ci < 5; ++ci) {
    size_t need = fixed + (size_t)cand[ci] * 262144;
    if (need <= ws_size) { CHUNK = cand[ci]; lgch = candl[ci]; break; }
  }
  int* zxq = (int*)ws;

  hipLaunchKernelGGL(k_cvt_embed, dim3(NV * ND / 4 / 256), dim3(256), 0, stream, embed, eb);
  hipLaunchKernelGGL(k_cvt_wi,    dim3(NH4 * ND / 256), dim3(256), 0, stream, wi, wit);
  hipLaunchKernelGGL(k_scale,     dim3(4), dim3(256), 0, stream, wh, dqv, rdq, rw);
  hipLaunchKernelGGL(k_cvt_whq,   dim3(1024), dim3(256), 0, stream, wh, rw, whq);

  for (int t0 = 0; t0 < NT; t0 += CHUNK) {
    hipLaunchKernelGGL(k_gemm_zx, dim3(CHUNK * 16), dim3(256), 0, stream,
                       tokens, eb, wit, rdq, zxq, t0, lgch);
    hipLaunchKernelGGL(k_lstm, dim3(32), dim3(512), 0, stream,
                       zxq, whq, dqv, bh, cst, hst, t0, CHUNK, lgch);
  }
  hipLaunchKernelGGL(k_out, dim3(NB), dim3(64), 0, stream, hst, wo, bo, y);
}

// Round 14
// 2229.193 us; speedup vs baseline: 2.0816x; 1.0233x over previous
//
#include <hip/hip_runtime.h>
#include <hip/hip_bf16.h>
#include <stdint.h>

typedef __hip_bfloat16 bf16;
typedef __attribute__((ext_vector_type(8))) short short8;
typedef __attribute__((ext_vector_type(4))) float f32x4;
typedef __attribute__((ext_vector_type(4))) int i32x4;
typedef __attribute__((ext_vector_type(4))) unsigned int u32x4;

#define NB   64
#define NT   2048
#define NV   32000
#define ND   256
#define NH4  1024
#define NCLS 27

// ---------------- dtype conversion / packing ----------------

__global__ __launch_bounds__(256) void k_cvt_embed(const float* __restrict__ e,
                                                   bf16* __restrict__ o) {
  int i = blockIdx.x * blockDim.x + threadIdx.x;
  float4 v = reinterpret_cast<const float4*>(e)[i];
  union { bf16 h[4]; uint2 u; } pk;
  pk.h[0] = __float2bfloat16(v.x);
  pk.h[1] = __float2bfloat16(v.y);
  pk.h[2] = __float2bfloat16(v.z);
  pk.h[3] = __float2bfloat16(v.w);
  reinterpret_cast<uint2*>(o)[i] = pk.u;
}

// Wi [256][1024] f32 -> Wi_t [1024][256] bf16
__global__ __launch_bounds__(256) void k_cvt_wi(const float* __restrict__ wi,
                                                bf16* __restrict__ wit) {
  int i = blockIdx.x * blockDim.x + threadIdx.x;
  int col = i >> 8;
  int k   = i & 255;
  wit[i] = __float2bfloat16(wi[k * NH4 + col]);
}

// per-column scales for i8 quantization of Wh.
__global__ __launch_bounds__(256) void k_scale(const float* __restrict__ wh,
                                               float* __restrict__ dq,
                                               float* __restrict__ rdq,
                                               float* __restrict__ rw) {
  int col = blockIdx.x * 256 + threadIdx.x;   // grid 4
  float m = 0.f;
  for (int k = 0; k < ND; ++k) m = fmaxf(m, fabsf(wh[k * NH4 + col]));
  dq[col]  = m * (1.f / 16129.f);
  rdq[col] = 16129.f / m;
  rw[col]  = 127.f / m;
}

// Wh -> i8 B-fragments for mfma_i32_16x16x64_i8
__global__ __launch_bounds__(256) void k_cvt_whq(const float* __restrict__ wh,
                                                 const float* __restrict__ rw,
                                                 signed char* __restrict__ whq) {
  int idx  = blockIdx.x * 256 + threadIdx.x;  // grid 1024
  int ii   = idx & 15;
  int lane = (idx >> 4) & 63;
  int kq   = (idx >> 10) & 3;
  int nt   = idx >> 12;
  int k   = kq * 64 + (lane >> 4) * 16 + ii;
  int col = nt * 16 + (lane & 15);
  whq[idx] = (signed char)(int)rintf(wh[k * NH4 + col] * rw[col]);
}

// ---------------- zx = embed[tokens] @ Wi, i32 dot-grid ----------------
// R14 layout: dword for (b, lt, col): ((p<<lgch)+lt)*2048 + (b&1)*1024
//   + (col&255)*4 + (col>>8)   where p=b>>1 — i.e. gate thread (b,u) reads
// its 4 gate pre-activations as ONE coalesced i32x4.
__global__ __launch_bounds__(256) void k_gemm_zx(const int*  __restrict__ tokens,
                                                 const bf16* __restrict__ eb,
                                                 const bf16* __restrict__ wit,
                                                 const float* __restrict__ rdq,
                                                 int* __restrict__ zxq,
                                                 int t0, int lgch) {
  __shared__ bf16 As[4 * 64 * 8];
  __shared__ bf16 Bs[4 * 64 * 8];
  int bid  = blockIdx.x;
  int nb   = bid & 15;
  int mb   = bid >> 4;          // step within chunk
  int n0   = nb * 64;
  int tid  = threadIdx.x, lane = tid & 63, wave = tid >> 6;
  int wm   = wave >> 1, wn = wave & 1;
  int srow = tid >> 2;          // batch 0..63
  int skg  = tid & 3;

  long trow = (long)tokens[srow * NT + t0 + mb] * ND;
  const bf16* ap = eb  + trow + skg * 8;
  const bf16* bp = wit + (long)(n0 + srow) * ND + skg * 8;
  bf16* as_dst = &As[(skg * 64 + srow) * 8];
  bf16* bs_dst = &Bs[(skg * 64 + srow) * 8];

  f32x4 acc[2][2] = {};
  for (int k0 = 0; k0 < ND; k0 += 32) {
    __syncthreads();
    *(u32x4*)as_dst = *(const u32x4*)(ap + k0);
    *(u32x4*)bs_dst = *(const u32x4*)(bp + k0);
    __syncthreads();
    short8 a0 = *(const short8*)&As[((lane >> 4) * 64 + wm * 32 +  0 + (lane & 15)) * 8];
    short8 a1 = *(const short8*)&As[((lane >> 4) * 64 + wm * 32 + 16 + (lane & 15)) * 8];
    short8 b0 = *(const short8*)&Bs[((lane >> 4) * 64 + wn * 32 +  0 + (lane & 15)) * 8];
    short8 b1 = *(const short8*)&Bs[((lane >> 4) * 64 + wn * 32 + 16 + (lane & 15)) * 8];
    acc[0][0] = __builtin_amdgcn_mfma_f32_16x16x32_bf16(a0, b0, acc[0][0], 0, 0, 0);
    acc[0][1] = __builtin_amdgcn_mfma_f32_16x16x32_bf16(a0, b1, acc[0][1], 0, 0, 0);
    acc[1][0] = __builtin_amdgcn_mfma_f32_16x16x32_bf16(a1, b0, acc[1][0], 0, 0, 0);
    acc[1][1] = __builtin_amdgcn_mfma_f32_16x16x32_bf16(a1, b1, acc[1][1], 0, 0, 0);
  }

  int cb  = n0 + wn * 32 + (lane & 15);
  float rq0 = rdq[cb], rq1 = rdq[cb + 16];
  int bb = wm * 32 + (lane >> 4) * 4;         // batch base (multiple of 4)
#pragma unroll
  for (int fm = 0; fm < 2; ++fm) {
#pragma unroll
    for (int fn = 0; fn < 2; ++fn) {
      int col = cb + fn * 16;
      int uu  = col & 255, q = col >> 8;
      float rq = fn ? rq1 : rq0;
#pragma unroll
      for (int i2 = 0; i2 < 4; ++i2) {
        int rr = bb + fm * 16 + i2;
        int p0 = rr >> 1;
        size_t idx = (((size_t)(p0 << lgch) + mb) * 2 + (rr & 1)) * 1024 + uu * 4 + q;
        zxq[idx] = (int)rintf(acc[fm][fn][i2] * rq);
      }
    }
  }
}

// ---------------- LSTM scan: fully CU-local, i8 MFMA, 32 WGs ----------------
// 32 WGs x 512 threads. WG p owns batches {2p, 2p+1} x ALL 256 units -> no
// inter-WG communication. Wh register-resident i8 (w[8][4] = 128 regs/wave).
// R14: MFMA chains start from ONE hoisted zero C-tuple (no per-j zc moves);
// zx is added in the GATE phase as a per-thread i32x4 in the same int grid
// (bit-identical to C-preload), depth-2 prefetched.
__device__ __forceinline__ float sigf(float x) {
  return __builtin_amdgcn_rcpf(1.f + __expf(-x));
}
__device__ __forceinline__ float tanh_fast(float x) {
  return 1.f - 2.f * __builtin_amdgcn_rcpf(1.f + __expf(2.f * x));
}

#define LSTM_STEP(ZX, ST)                                                       \
  {                                                                             \
    i32x4 a0 = *(const i32x4*)&aF[0 * 1024 + l * 16];                           \
    i32x4 a1 = *(const i32x4*)&aF[1 * 1024 + l * 16];                           \
    i32x4 a2 = *(const i32x4*)&aF[2 * 1024 + l * 16];                           \
    i32x4 a3 = *(const i32x4*)&aF[3 * 1024 + l * 16];                           \
    i32x4 acc[8];                                                               \
    _Pragma("unroll")                                                           \
    for (int j = 0; j < 8; ++j) {                                               \
      i32x4 t;                                                                  \
      t = __builtin_amdgcn_mfma_i32_16x16x64_i8(a0, w[j][0], czero, 0, 0, 0);   \
      t = __builtin_amdgcn_mfma_i32_16x16x64_i8(a1, w[j][1], t, 0, 0, 0);       \
      t = __builtin_amdgcn_mfma_i32_16x16x64_i8(a2, w[j][2], t, 0, 0, 0);       \
      acc[j] = __builtin_amdgcn_mfma_i32_16x16x64_i8(a3, w[j][3], t, 0, 0, 0);  \
    }                                                                           \
    if (l4 == 0) {                                                              \
      _Pragma("unroll")                                                         \
      for (int j = 0; j < 8; ++j) {                                             \
        int col = (wv * 8 + j) * 16 + l15;                                      \
        int tt  = ((col & 255) << 2) | (col >> 8);                              \
        zl[tt]        = acc[j][0];                                              \
        zl[1024 + tt] = acc[j][1];                                              \
      }                                                                         \
    }                                                                           \
    __syncthreads();                                                            \
    {                                                                           \
      i32x4 zr = *(const i32x4*)&zl[b * 1024 + u * 4];                          \
      int s0 = zr[0] + ZX[0];                                                   \
      int s1 = zr[1] + ZX[1];                                                   \
      int s2 = zr[2] + ZX[2];                                                   \
      int s3 = zr[3] + ZX[3];                                                   \
      if ((ST) + 2 < tn)                                                        \
        ZX = *(const i32x4*)(zg + (size_t)((ST) + 2) * 2048);                   \
      float zi = (float)s0 * dqv[0] + bhv[0];                                   \
      float zf = (float)s1 * dqv[1] + bhv[1];                                   \
      float zg_ = (float)s2 * dqv[2] + bhv[2];                                  \
      float zo = (float)s3 * dqv[3] + bhv[3];                                   \
      c = sigf(zf) * c + sigf(zi) * tanh_fast(zg_);                             \
      float h = sigf(zo) * tanh_fast(c);                                        \
      aF[kqu * 1024 + (b | (lgu << 4)) * 16 + iiu] =                            \
          (signed char)(int)rintf(h * 127.f);                                   \
      if ((ST) == tn - 1) hst[(p * 2 + b) * 256 + u] = h;                       \
    }                                                                           \
    __syncthreads();                                                            \
  }

__global__ __launch_bounds__(512, 1) void k_lstm(const int* __restrict__ zxq,
                                                 const signed char* __restrict__ whq,
                                                 const float* __restrict__ dq,
                                                 const float* __restrict__ bh,
                                                 float* __restrict__ cst,
                                                 float* __restrict__ hst,
                                                 int t0, int tn, int lgch) {
  __shared__ int  zl[2 * 1024];            // [b][u*4+q] i32 (transposed), 8 KB
  __shared__ signed char aF[4 * 64 * 16];  // [kq][la][16] i8 A-frags, 4 KB

  int p   = blockIdx.x;        // batches {2p, 2p+1}
  int tid = threadIdx.x;
  int l   = tid & 63;
  int wv  = tid >> 6;
  int l15 = l & 15, l4 = l >> 4;
  int u   = tid & 255;         // gate-phase unit
  int b   = tid >> 8;          // gate-phase batch 0/1

  // register-resident Wh i8 B-fragments (static indices only)
  i32x4 w[8][4];
#pragma unroll
  for (int j = 0; j < 8; ++j) {
    int nt = wv * 8 + j;
#pragma unroll
    for (int kq = 0; kq < 4; ++kq)
      w[j][kq] = *(const i32x4*)&whq[((nt * 4 + kq) * 64 + l) * 16];
  }
#pragma unroll
  for (int j = 0; j < 8; ++j)
#pragma unroll
    for (int kq = 0; kq < 4; ++kq)
      asm volatile("" : "+v"(w[j][kq]));

  // hoisted zero C-tuple (materialized once; pinned so it can't be sunk)
  i32x4 czero = (i32x4)0;
  asm volatile("" : "+v"(czero));

  float dqv[4], bhv[4];
#pragma unroll
  for (int q = 0; q < 4; ++q) { dqv[q] = dq[q * 256 + u]; bhv[q] = bh[q * 256 + u]; }
  float c = (t0 == 0) ? 0.f : cst[(p * 2 + b) * 256 + u];

  int kqu = u >> 6, lgu = (u >> 4) & 3, iiu = u & 15;

  // zero A-frag LDS (pad rows 2..15 stay zero forever)
  if (tid < 256) ((i32x4*)aF)[tid] = (i32x4)0;
  __syncthreads();
  if (t0 != 0) {
    int hq = (int)rintf(hst[(p * 2 + b) * 256 + u] * 127.f);
    aF[kqu * 1024 + (b | (lgu << 4)) * 16 + iiu] = (signed char)hq;
  }
  __syncthreads();

  // per-thread zx base; depth-2 preload (steps 0 and 1)
  const int* zg = zxq + ((size_t)(p << lgch) * 2 + b) * 1024 + u * 4;
  i32x4 zxA = *(const i32x4*)zg;
  i32x4 zxB = *(const i32x4*)(zg + 2048);

  for (int lt = 0; lt < tn; lt += 2) {
    LSTM_STEP(zxA, lt)
    LSTM_STEP(zxB, lt + 1)
  }

  cst[(p * 2 + b) * 256 + u] = c;
}

// ---------------- y = h @ Wo + bo ----------------
__global__ __launch_bounds__(64) void k_out(const float* __restrict__ hfin,
                                            const float* __restrict__ wo,
                                            const float* __restrict__ bo,
                                            float* __restrict__ y) {
  __shared__ float hsm[256];
  int b = blockIdx.x, tid = threadIdx.x;
  for (int i = tid; i < 256; i += 64) hsm[i] = hfin[b * 256 + i];
  __syncthreads();
  if (tid < NCLS) {
    float s = bo[tid];
    for (int k = 0; k < 256; ++k) s += hsm[k] * wo[k * NCLS + tid];
    y[b * NCLS + tid] = s;
  }
}

// ---------------- launcher ----------------
extern "C" void kernel_launch(void* const* d_in, const int* in_sizes, int n_in,
                              void* d_out, int out_size, void* d_ws, size_t ws_size,
                              hipStream_t stream) {
  const int*   tokens = (const int*)d_in[0];
  const float* embed  = (const float*)d_in[3];
  const float* wi     = (const float*)d_in[4];
  const float* wh     = (const float*)d_in[5];
  const float* bh     = (const float*)d_in[6];
  const float* wo     = (const float*)d_in[7];
  const float* bo     = (const float*)d_in[8];
  float* y = (float*)d_out;

  char* ws = (char*)d_ws;
  bf16* eb        = (bf16*)ws;        ws += (size_t)NV * ND * 2;    // 16.38 MB
  bf16* wit       = (bf16*)ws;        ws += (size_t)NH4 * ND * 2;   // 0.5 MB
  signed char* whq = (signed char*)ws; ws += (size_t)ND * NH4;      // 0.25 MB
  float* dqv      = (float*)ws;       ws += (size_t)NH4 * 4;        // 4 KB
  float* rdq      = (float*)ws;       ws += (size_t)NH4 * 4;        // 4 KB
  float* rw       = (float*)ws;       ws += (size_t)NH4 * 4;        // 4 KB
  float* cst      = (float*)ws;       ws += (size_t)NB * ND * 4;    // 64 KB
  float* hst      = (float*)ws;       ws += (size_t)NB * ND * 4;    // 64 KB
  size_t fixed = (size_t)(ws - (char*)d_ws);

  // zxq (i32): CH steps x 32 p-groups x 8KB = CH x 256 KB
  int CHUNK = 32, lgch = 5;
  static const int cand[]  = {512, 256, 128, 64, 32};
  static const int candl[] = {9, 8, 7, 6, 5};
  for (int ci = 0; ci < 5; ++ci) {
    size_t need = fixed + (size_t)cand[ci] * 262144;
    if (need <= ws_size) { CHUNK = cand[ci]; lgch = candl[ci]; break; }
  }
  int* zxq = (int*)ws;

  hipLaunchKernelGGL(k_cvt_embed, dim3(NV * ND / 4 / 256), dim3(256), 0, stream, embed, eb);
  hipLaunchKernelGGL(k_cvt_wi,    dim3(NH4 * ND / 256), dim3(256), 0, stream, wi, wit);
  hipLaunchKernelGGL(k_scale,     dim3(4), dim3(256), 0, stream, wh, dqv, rdq, rw);
  hipLaunchKernelGGL(k_cvt_whq,   dim3(1024), dim3(256), 0, stream, wh, rw, whq);

  for (int t0 = 0; t0 < NT; t0 += CHUNK) {
    hipLaunchKernelGGL(k_gemm_zx, dim3(CHUNK * 16), dim3(256), 0, stream,
                       tokens, eb, wit, rdq, zxq, t0, lgch);
    hipLaunchKernelGGL(k_lstm, dim3(32), dim3(512), 0, stream,
                       zxq, whq, dqv, bh, cst, hst, t0, CHUNK, lgch);
  }
  hipLaunchKernelGGL(k_out, dim3(NB), dim3(64), 0, stream, hst, wo, bo, y);
}

// Round 15
// 2161.784 us; speedup vs baseline: 2.1465x; 1.0312x over previous
//
#include <hip/hip_runtime.h>
#include <hip/hip_bf16.h>
#include <stdint.h>

typedef __hip_bfloat16 bf16;
typedef __attribute__((ext_vector_type(8))) short short8;
typedef __attribute__((ext_vector_type(4))) float f32x4;
typedef __attribute__((ext_vector_type(4))) int i32x4;
typedef __attribute__((ext_vector_type(4))) unsigned int u32x4;

#define NB   64
#define NT   2048
#define NV   32000
#define ND   256
#define NH4  1024
#define NCLS 27
#define CH   256          // time chunk (double-buffered)
#define NCH  (NT / CH)    // 8

// ---------------- dtype conversion / packing ----------------

__global__ __launch_bounds__(256) void k_cvt_embed(const float* __restrict__ e,
                                                   bf16* __restrict__ o) {
  int i = blockIdx.x * blockDim.x + threadIdx.x;
  float4 v = reinterpret_cast<const float4*>(e)[i];
  union { bf16 h[4]; uint2 u; } pk;
  pk.h[0] = __float2bfloat16(v.x);
  pk.h[1] = __float2bfloat16(v.y);
  pk.h[2] = __float2bfloat16(v.z);
  pk.h[3] = __float2bfloat16(v.w);
  reinterpret_cast<uint2*>(o)[i] = pk.u;
}

// Wi [256][1024] f32 -> Wi_t [1024][256] bf16
__global__ __launch_bounds__(256) void k_cvt_wi(const float* __restrict__ wi,
                                                bf16* __restrict__ wit) {
  int i = blockIdx.x * blockDim.x + threadIdx.x;
  int col = i >> 8;
  int k   = i & 255;
  wit[i] = __float2bfloat16(wi[k * NH4 + col]);
}

// per-column scales for i8 quantization of Wh.
__global__ __launch_bounds__(256) void k_scale(const float* __restrict__ wh,
                                               float* __restrict__ dq,
                                               float* __restrict__ rdq,
                                               float* __restrict__ rw) {
  int col = blockIdx.x * 256 + threadIdx.x;   // grid 4
  float m = 0.f;
  for (int k = 0; k < ND; ++k) m = fmaxf(m, fabsf(wh[k * NH4 + col]));
  dq[col]  = m * (1.f / 16129.f);
  rdq[col] = 16129.f / m;
  rw[col]  = 127.f / m;
}

// Wh -> i8 B-fragments for mfma_i32_16x16x64_i8
__global__ __launch_bounds__(256) void k_cvt_whq(const float* __restrict__ wh,
                                                 const float* __restrict__ rw,
                                                 signed char* __restrict__ whq) {
  int idx  = blockIdx.x * 256 + threadIdx.x;  // grid 1024
  int ii   = idx & 15;
  int lane = (idx >> 4) & 63;
  int kq   = (idx >> 10) & 3;
  int nt   = idx >> 12;
  int k   = kq * 64 + (lane >> 4) * 16 + ii;
  int col = nt * 16 + (lane & 15);
  whq[idx] = (signed char)(int)rintf(wh[k * NH4 + col] * rw[col]);
}

// ---------------- gate helpers ----------------
__device__ __forceinline__ float sigf(float x) {
  return __builtin_amdgcn_rcpf(1.f + __expf(-x));
}
__device__ __forceinline__ float tanh_fast(float x) {
  return 1.f - 2.f * __builtin_amdgcn_rcpf(1.f + __expf(2.f * x));
}

#define LSTM_STEP(ZX, ST)                                                       \
  {                                                                             \
    i32x4 a0 = *(const i32x4*)&aF[0 * 1024 + l * 16];                           \
    i32x4 a1 = *(const i32x4*)&aF[1 * 1024 + l * 16];                           \
    i32x4 a2 = *(const i32x4*)&aF[2 * 1024 + l * 16];                           \
    i32x4 a3 = *(const i32x4*)&aF[3 * 1024 + l * 16];                           \
    i32x4 acc[8];                                                               \
    _Pragma("unroll")                                                           \
    for (int j = 0; j < 8; ++j) {                                               \
      i32x4 t;                                                                  \
      t = __builtin_amdgcn_mfma_i32_16x16x64_i8(a0, w[j][0], czero, 0, 0, 0);   \
      t = __builtin_amdgcn_mfma_i32_16x16x64_i8(a1, w[j][1], t, 0, 0, 0);       \
      t = __builtin_amdgcn_mfma_i32_16x16x64_i8(a2, w[j][2], t, 0, 0, 0);       \
      acc[j] = __builtin_amdgcn_mfma_i32_16x16x64_i8(a3, w[j][3], t, 0, 0, 0);  \
    }                                                                           \
    if (l4 == 0) {                                                              \
      _Pragma("unroll")                                                         \
      for (int j = 0; j < 8; ++j) {                                             \
        int col = (wv * 8 + j) * 16 + l15;                                      \
        int tt  = ((col & 255) << 2) | (col >> 8);                              \
        zl[tt]        = acc[j][0];                                              \
        zl[1024 + tt] = acc[j][1];                                              \
      }                                                                         \
    }                                                                           \
    __syncthreads();                                                            \
    {                                                                           \
      i32x4 zr = *(const i32x4*)&zl[b * 1024 + u * 4];                          \
      int s0 = zr[0] + ZX[0];                                                   \
      int s1 = zr[1] + ZX[1];                                                   \
      int s2 = zr[2] + ZX[2];                                                   \
      int s3 = zr[3] + ZX[3];                                                   \
      if ((ST) + 2 < CH)                                                        \
        ZX = *(const i32x4*)(zg + (size_t)((ST) + 2) * 2048);                   \
      float zi = (float)s0 * dqv[0] + bhv[0];                                   \
      float zf = (float)s1 * dqv[1] + bhv[1];                                   \
      float zg_ = (float)s2 * dqv[2] + bhv[2];                                  \
      float zo = (float)s3 * dqv[3] + bhv[3];                                   \
      c = sigf(zf) * c + sigf(zi) * tanh_fast(zg_);                             \
      float h = sigf(zo) * tanh_fast(c);                                        \
      aF[kqu * 1024 + (b | (lgu << 4)) * 16 + iiu] =                            \
          (signed char)(int)rintf(h * 127.f);                                   \
      if ((ST) == CH - 1) hst[(p * 2 + b) * 256 + u] = h;                       \
    }                                                                           \
    __syncthreads();                                                            \
  }

// ---------------- fused pipelined kernel ----------------
// Launch L (L = 0..NCH):
//   blocks 0..31   : LSTM-scan chunk L-1 (skip at L==0), reads zx buf (L-1)&1
//   blocks 32..159 : zx-GEMM chunk L (skip at L==NCH), writes zx buf L&1
// Roles touch disjoint buffers; visibility across launches is kernel-boundary.
// Scan blocks are fully independent (no co-residency requirement).
__global__ __launch_bounds__(512, 1) void k_fused(const int*  __restrict__ tokens,
                                                  const bf16* __restrict__ eb,
                                                  const bf16* __restrict__ wit,
                                                  const float* __restrict__ rdq,
                                                  const signed char* __restrict__ whq,
                                                  const float* __restrict__ dq,
                                                  const float* __restrict__ bh,
                                                  float* __restrict__ cst,
                                                  float* __restrict__ hst,
                                                  int* __restrict__ zxqA,
                                                  int* __restrict__ zxqB,
                                                  int L) {
  __shared__ char smem[16384];
  int bid = blockIdx.x;

  if (bid < 32) {
    // ================= scan role: chunk L-1 =================
    if (L == 0) return;
    int* zl = (int*)smem;                           // [b][u*4+q] i32, 8 KB
    signed char* aF = (signed char*)(smem + 8192);  // [kq][la][16] i8, 4 KB
    const int* __restrict__ zxq = ((L - 1) & 1) ? zxqB : zxqA;
    int t0 = (L - 1) * CH;

    int p   = bid;               // batches {2p, 2p+1}
    int tid = threadIdx.x;
    int l   = tid & 63;
    int wv  = tid >> 6;
    int l15 = l & 15, l4 = l >> 4;
    int u   = tid & 255;         // gate-phase unit
    int b   = tid >> 8;          // gate-phase batch 0/1

    // register-resident Wh i8 B-fragments (static indices only)
    i32x4 w[8][4];
#pragma unroll
    for (int j = 0; j < 8; ++j) {
      int nt = wv * 8 + j;
#pragma unroll
      for (int kq = 0; kq < 4; ++kq)
        w[j][kq] = *(const i32x4*)&whq[((nt * 4 + kq) * 64 + l) * 16];
    }
#pragma unroll
    for (int j = 0; j < 8; ++j)
#pragma unroll
      for (int kq = 0; kq < 4; ++kq)
        asm volatile("" : "+v"(w[j][kq]));

    i32x4 czero = (i32x4)0;
    asm volatile("" : "+v"(czero));

    float dqv[4], bhv[4];
#pragma unroll
    for (int q = 0; q < 4; ++q) { dqv[q] = dq[q * 256 + u]; bhv[q] = bh[q * 256 + u]; }
    float c = (t0 == 0) ? 0.f : cst[(p * 2 + b) * 256 + u];

    int kqu = u >> 6, lgu = (u >> 4) & 3, iiu = u & 15;

    if (tid < 256) ((i32x4*)aF)[tid] = (i32x4)0;
    __syncthreads();
    if (t0 != 0) {
      int hq = (int)rintf(hst[(p * 2 + b) * 256 + u] * 127.f);
      aF[kqu * 1024 + (b | (lgu << 4)) * 16 + iiu] = (signed char)hq;
    }
    __syncthreads();

    // per-thread zx base; depth-2 preload
    const int* zg = zxq + ((size_t)(p * CH) * 2 + b) * 1024 + u * 4;
    i32x4 zxA = *(const i32x4*)zg;
    i32x4 zxB = *(const i32x4*)(zg + 2048);

    for (int lt = 0; lt < CH; lt += 2) {
      LSTM_STEP(zxA, lt)
      LSTM_STEP(zxB, lt + 1)
    }

    cst[(p * 2 + b) * 256 + u] = c;

  } else {
    // ================= gemm role: chunk L =================
    if (L >= NCH) return;
    int* __restrict__ zxw = (L & 1) ? zxqB : zxqA;
    int t0 = L * CH;
    int hh   = threadIdx.x >> 8;          // half 0/1
    int tid2 = threadIdx.x & 255;
    bf16* As = (bf16*)(smem + hh * 8192);
    bf16* Bs = (bf16*)(smem + hh * 8192 + 4096);

    int lane = tid2 & 63, wave = tid2 >> 6;
    int wm   = wave >> 1, wn = wave & 1;
    int srow = tid2 >> 2;          // batch 0..63
    int skg  = tid2 & 3;
    bf16* as_dst = &As[(skg * 64 + srow) * 8];
    bf16* bs_dst = &Bs[(skg * 64 + srow) * 8];

    for (int it = 0; it < 16; ++it) {
      int tg = ((bid - 32) + it * 128) * 2 + hh;   // 0..4095
      int mb = tg >> 4;            // step within chunk
      int nb = tg & 15;
      int n0 = nb * 64;

      long trow = (long)tokens[srow * NT + t0 + mb] * ND;
      const bf16* ap = eb  + trow + skg * 8;
      const bf16* bp = wit + (long)(n0 + srow) * ND + skg * 8;

      f32x4 acc[2][2] = {};
      for (int k0 = 0; k0 < ND; k0 += 32) {
        __syncthreads();
        *(u32x4*)as_dst = *(const u32x4*)(ap + k0);
        *(u32x4*)bs_dst = *(const u32x4*)(bp + k0);
        __syncthreads();
        short8 a0 = *(const short8*)&As[((lane >> 4) * 64 + wm * 32 +  0 + (lane & 15)) * 8];
        short8 a1 = *(const short8*)&As[((lane >> 4) * 64 + wm * 32 + 16 + (lane & 15)) * 8];
        short8 b0 = *(const short8*)&Bs[((lane >> 4) * 64 + wn * 32 +  0 + (lane & 15)) * 8];
        short8 b1 = *(const short8*)&Bs[((lane >> 4) * 64 + wn * 32 + 16 + (lane & 15)) * 8];
        acc[0][0] = __builtin_amdgcn_mfma_f32_16x16x32_bf16(a0, b0, acc[0][0], 0, 0, 0);
        acc[0][1] = __builtin_amdgcn_mfma_f32_16x16x32_bf16(a0, b1, acc[0][1], 0, 0, 0);
        acc[1][0] = __builtin_amdgcn_mfma_f32_16x16x32_bf16(a1, b0, acc[1][0], 0, 0, 0);
        acc[1][1] = __builtin_amdgcn_mfma_f32_16x16x32_bf16(a1, b1, acc[1][1], 0, 0, 0);
      }

      int cb  = n0 + wn * 32 + (lane & 15);
      float rq0 = rdq[cb], rq1 = rdq[cb + 16];
      int bb = wm * 32 + (lane >> 4) * 4;
#pragma unroll
      for (int fm = 0; fm < 2; ++fm) {
#pragma unroll
        for (int fn = 0; fn < 2; ++fn) {
          int col = cb + fn * 16;
          int uu  = col & 255, q = col >> 8;
          float rq = fn ? rq1 : rq0;
#pragma unroll
          for (int i2 = 0; i2 < 4; ++i2) {
            int rr = bb + fm * 16 + i2;
            int p0 = rr >> 1;
            size_t idx = (((size_t)(p0 * CH) + mb) * 2 + (rr & 1)) * 1024 + uu * 4 + q;
            zxw[idx] = (int)rintf(acc[fm][fn][i2] * rq);
          }
        }
      }
    }
  }
}

// ---------------- y = h @ Wo + bo ----------------
__global__ __launch_bounds__(64) void k_out(const float* __restrict__ hfin,
                                            const float* __restrict__ wo,
                                            const float* __restrict__ bo,
                                            float* __restrict__ y) {
  __shared__ float hsm[256];
  int b = blockIdx.x, tid = threadIdx.x;
  for (int i = tid; i < 256; i += 64) hsm[i] = hfin[b * 256 + i];
  __syncthreads();
  if (tid < NCLS) {
    float s = bo[tid];
    for (int k = 0; k < 256; ++k) s += hsm[k] * wo[k * NCLS + tid];
    y[b * NCLS + tid] = s;
  }
}

// ---------------- launcher ----------------
extern "C" void kernel_launch(void* const* d_in, const int* in_sizes, int n_in,
                              void* d_out, int out_size, void* d_ws, size_t ws_size,
                              hipStream_t stream) {
  const int*   tokens = (const int*)d_in[0];
  const float* embed  = (const float*)d_in[3];
  const float* wi     = (const float*)d_in[4];
  const float* wh     = (const float*)d_in[5];
  const float* bh     = (const float*)d_in[6];
  const float* wo     = (const float*)d_in[7];
  const float* bo     = (const float*)d_in[8];
  float* y = (float*)d_out;

  char* ws = (char*)d_ws;
  bf16* eb         = (bf16*)ws;        ws += (size_t)NV * ND * 2;    // 16.38 MB
  bf16* wit        = (bf16*)ws;        ws += (size_t)NH4 * ND * 2;   // 0.5 MB
  signed char* whq = (signed char*)ws; ws += (size_t)ND * NH4;       // 0.25 MB
  float* dqv       = (float*)ws;       ws += (size_t)NH4 * 4;        // 4 KB
  float* rdq       = (float*)ws;       ws += (size_t)NH4 * 4;        // 4 KB
  float* rw        = (float*)ws;       ws += (size_t)NH4 * 4;        // 4 KB
  float* cst       = (float*)ws;       ws += (size_t)NB * ND * 4;    // 64 KB
  float* hst       = (float*)ws;       ws += (size_t)NB * ND * 4;    // 64 KB
  int* zxqA        = (int*)ws;         ws += (size_t)CH * 262144;    // 64 MB
  int* zxqB        = (int*)ws;         ws += (size_t)CH * 262144;    // 64 MB
  // total ≈ 145.6 MB (< R11-14's proven 151.8 MB footprint)

  hipLaunchKernelGGL(k_cvt_embed, dim3(NV * ND / 4 / 256), dim3(256), 0, stream, embed, eb);
  hipLaunchKernelGGL(k_cvt_wi,    dim3(NH4 * ND / 256), dim3(256), 0, stream, wi, wit);
  hipLaunchKernelGGL(k_scale,     dim3(4), dim3(256), 0, stream, wh, dqv, rdq, rw);
  hipLaunchKernelGGL(k_cvt_whq,   dim3(1024), dim3(256), 0, stream, wh, rw, whq);

  for (int L = 0; L <= NCH; ++L) {
    hipLaunchKernelGGL(k_fused, dim3(160), dim3(512), 0, stream,
                       tokens, eb, wit, rdq, whq, dqv, bh, cst, hst,
                       zxqA, zxqB, L);
  }
  hipLaunchKernelGGL(k_out, dim3(NB), dim3(64), 0, stream, hst, wo, bo, y);
}